// Round 12
// baseline (166.576 us; speedup 1.0000x reference)
//
#include <hip/hip_runtime.h>

typedef unsigned short u16;
typedef __attribute__((ext_vector_type(8))) short bf16x8;
typedef __attribute__((ext_vector_type(4))) float f32x4;

#define LOG2E 1.4426950408889634f

__device__ __forceinline__ float bf2f(u16 v) {
    union { unsigned u; float f; } x; x.u = ((unsigned)v) << 16; return x.f;
}
__device__ __forceinline__ u16 f2bf(float f) {
    union { float f; unsigned u; } x; x.f = f;
    unsigned u = x.u;
    u += 0x7FFFu + ((u >> 16) & 1u);   // round-to-nearest-even
    return (u16)(u >> 16);
}
__device__ __forceinline__ float sigm(float x) {
    return __builtin_amdgcn_rcpf(1.f + __builtin_amdgcn_exp2f(-x * LOG2E));
}
__device__ __forceinline__ float tanh_fast(float y) {
    float e = __builtin_amdgcn_exp2f(y * (2.f * LOG2E));
    return 1.f - 2.f * __builtin_amdgcn_rcpf(e + 1.f);   // saturates to +-1 safely
}
// raw barrier: LDS visibility only, NO vmem drain
#define STEP_BAR() asm volatile("s_waitcnt lgkmcnt(0)\ns_barrier" ::: "memory")

// ---------------------------------------------------------------------------
// K0: fold cross projection into GRU input weights. (unchanged)
// ---------------------------------------------------------------------------
__global__ __launch_bounds__(256)
void k0_fuse(const float* __restrict__ wihf, const float* __restrict__ bihf,
             const float* __restrict__ wihb, const float* __restrict__ bihb,
             const float* __restrict__ cw, const float* __restrict__ cb,
             u16* __restrict__ Wf, float* __restrict__ Bf)
{
    const int z  = blockIdx.x / 96;
    const int n0 = (blockIdx.x % 96) * 4;
    const int j  = threadIdx.x;
    const float* W   = z ? wihb : wihf;
    const float* bih = z ? bihb : bihf;

    __shared__ float red[256];

    float a0 = 0.f, a1 = 0.f, a2 = 0.f, a3 = 0.f;
    for (int k = 0; k < 256; k++) {
        float cv = cw[(size_t)k * 256 + j];
        a0 += W[(size_t)(n0 + 0) * 256 + k] * cv;
        a1 += W[(size_t)(n0 + 1) * 256 + k] * cv;
        a2 += W[(size_t)(n0 + 2) * 256 + k] * cv;
        a3 += W[(size_t)(n0 + 3) * 256 + k] * cv;
    }
    u16* wout = Wf + ((size_t)z * 384 + n0) * 256 + j;
    wout[0]   = f2bf(a0);
    wout[256] = f2bf(a1);
    wout[512] = f2bf(a2);
    wout[768] = f2bf(a3);

    float cbv = cb[j];
    #pragma unroll
    for (int i = 0; i < 4; i++) {
        red[j] = W[(size_t)(n0 + i) * 256 + j] * cbv;
        __syncthreads();
        if (j < 64) red[j] += red[j + 64] + red[j + 128] + red[j + 192];
        __syncthreads();
        if (j == 0) {
            float s = 0.f;
            for (int t = 0; t < 64; t++) s += red[t];
            Bf[z * 384 + n0 + i] = s + bih[n0 + i];
        }
        __syncthreads();
    }
}

// ---------------------------------------------------------------------------
// K1: time-kernel attention, zero-LDS main loop. (unchanged)
// ---------------------------------------------------------------------------
__global__ __launch_bounds__(1024)
void k1_attn(const float* __restrict__ x, const float* __restrict__ ts,
             const float* __restrict__ qy, const float* __restrict__ bww,
             u16* __restrict__ aout)
{
    const int b   = blockIdx.x >> 5;
    const int q0  = (blockIdx.x & 31) * 4;
    const int tid = threadIdx.x;
    const int d   = tid & 255;
    const int sh  = (tid >> 8) & 1;
    const int qp  = tid >> 9;
    const int dm  = 128 + (d & 127);

    __shared__ float red[4][512];

    float w  = bww[d];
    float kk = log1pf(expf(w)) * LOG2E;
    float qv0 = qy[q0 + qp * 2], qv1 = qy[q0 + qp * 2 + 1];
    float A0 = -kk * qv0 * qv0, B0 = 2.f * kk * qv0;
    float A1 = -kk * qv1 * qv1, B1 = 2.f * kk * qv1;
    float C  = -kk;

    const float* xb = x + (size_t)b * 512 * 256;
    const float* tb = ts + b * 512;

    float n0 = 0.f, n1 = 0.f, d0 = 0.f, d1 = 0.f;
    const int s0 = sh * 256;
    #pragma unroll 4
    for (int s = s0; s < s0 + 256; s++) {
        float xv = xb[(size_t)s * 256 + d];
        float mv = xb[(size_t)s * 256 + dm];
        float t  = tb[s];
        float ct  = C * t;
        float mxv = mv * xv;
        float p0 = __builtin_amdgcn_exp2f(A0 + t * (B0 + ct));
        float p1 = __builtin_amdgcn_exp2f(A1 + t * (B1 + ct));
        n0 += p0 * mxv;  d0 += p0 * mv;
        n1 += p1 * mxv;  d1 += p1 * mv;
    }

    if (sh == 1) {
        int u = qp * 256 + d;
        red[0][u] = n0; red[1][u] = n1; red[2][u] = d0; red[3][u] = d1;
    }
    __syncthreads();
    if (sh == 0) {
        int u = qp * 256 + d;
        n0 += red[0][u]; n1 += red[1][u]; d0 += red[2][u]; d1 += red[3][u];
        float r0 = n0 / fmaxf(d0, 1e-30f);
        float r1 = n1 / fmaxf(d1, 1e-30f);
        aout[(size_t)(b * 128 + q0 + qp * 2 + 0) * 256 + d] = f2bf(r0);
        aout[(size_t)(b * 128 + q0 + qp * 2 + 1) * 256 + d] = f2bf(r1);
    }
}

// ---------------------------------------------------------------------------
// K2: xp2 = aout @ Wf^T + Bf via MFMA. (unchanged)
// ---------------------------------------------------------------------------
__global__ __launch_bounds__(256)
void k2_xp(const u16* __restrict__ aout,
           const u16* __restrict__ Wf, const float* __restrict__ Bf,
           u16* __restrict__ xp2)    // [2][128][3][128][8] bf16
{
    const int wid  = threadIdx.x >> 6;
    const int lane = threadIdx.x & 63;
    int gw = blockIdx.x * 4 + wid;
    int z  = (gw >= 1536) ? 1 : 0;
    int t  = gw - z * 1536;
    int rt = t / 24, nt = t - rt * 24;
    int r0 = rt * 16, n0 = nt * 16;

    const u16*   W  = Wf + (size_t)z * 384 * 256;
    const float* Bv = Bf + z * 384;

    const u16* arow = aout + (size_t)(r0 + (lane & 15)) * 256 + (lane >> 4) * 8;
    const u16* brow = W    + (size_t)(n0 + (lane & 15)) * 256 + (lane >> 4) * 8;

    f32x4 acc = {0.f, 0.f, 0.f, 0.f};
    #pragma unroll
    for (int k = 0; k < 8; k++) {
        bf16x8 a     = *(const bf16x8*)(arow + k * 32);
        bf16x8 bfrag = *(const bf16x8*)(brow + k * 32);
        acc = __builtin_amdgcn_mfma_f32_16x16x32_bf16(a, bfrag, acc, 0, 0, 0);
    }
    int col   = n0 + (lane & 15);
    int rbase = r0 + (lane >> 4) * 4;
    float bias = Bv[col];
    int g  = col >> 7;
    int dv = col & 127;
    u16* xpz = xp2 + (size_t)z * 393216;
    #pragma unroll
    for (int i = 0; i < 4; i++) {
        int r  = rbase + i;
        int bb = r >> 7;
        int tt = r & 127;
        int tau = z ? (127 - tt) : tt;
        xpz[((size_t)(tau * 3 + g) * 128 + dv) * 8 + bb] = f2bf(acc[i] + bias);
    }
}

// ---------------------------------------------------------------------------
// K3: bidirectional GRU with SKEWED batch pipeline.
// 8 blocks = (dir z, batch-pair bp), 512 thr (8 waves). The two batches are
// independent recurrences run half-step out of phase:
//   phase 2c  : issue MFMA_A(step c)   || gate_B(step c-1)
//   phase 2c+1: issue MFMA_B(step c)   || gate_A(step c)
// MFMA results get a full phase to drain before their gate reads them; the
// gate TRANS chain overlaps the other batch's MFMA issue. hist = 1 slot per
// batch (write->barrier->read; same-phase ops touch different slots).
// A-frag: all lanes broadcast-read row 0 (C rows 1-15 unread garbage).
// ---------------------------------------------------------------------------
#define K3_MFMA(SLOT, AC0, AC1, AC2) {                                        \
    bf16x8 A0 = *(const bf16x8*)&hist[SLOT][kb];                              \
    bf16x8 A1 = *(const bf16x8*)&hist[SLOT][32 + kb];                         \
    bf16x8 A2 = *(const bf16x8*)&hist[SLOT][64 + kb];                         \
    bf16x8 A3 = *(const bf16x8*)&hist[SLOT][96 + kb];                         \
    AC0 = zero4; AC1 = zero4; AC2 = zero4;                                    \
    AC0 = __builtin_amdgcn_mfma_f32_16x16x32_bf16(A0, Whi[0][0], AC0, 0,0,0); \
    AC1 = __builtin_amdgcn_mfma_f32_16x16x32_bf16(A0, Whi[1][0], AC1, 0,0,0); \
    AC2 = __builtin_amdgcn_mfma_f32_16x16x32_bf16(A0, Whi[2][0], AC2, 0,0,0); \
    AC0 = __builtin_amdgcn_mfma_f32_16x16x32_bf16(A1, Whi[0][1], AC0, 0,0,0); \
    AC1 = __builtin_amdgcn_mfma_f32_16x16x32_bf16(A1, Whi[1][1], AC1, 0,0,0); \
    AC2 = __builtin_amdgcn_mfma_f32_16x16x32_bf16(A1, Whi[2][1], AC2, 0,0,0); \
    AC0 = __builtin_amdgcn_mfma_f32_16x16x32_bf16(A2, Whi[0][2], AC0, 0,0,0); \
    AC1 = __builtin_amdgcn_mfma_f32_16x16x32_bf16(A2, Whi[1][2], AC1, 0,0,0); \
    AC2 = __builtin_amdgcn_mfma_f32_16x16x32_bf16(A2, Whi[2][2], AC2, 0,0,0); \
    AC0 = __builtin_amdgcn_mfma_f32_16x16x32_bf16(A3, Whi[0][3], AC0, 0,0,0); \
    AC1 = __builtin_amdgcn_mfma_f32_16x16x32_bf16(A3, Whi[1][3], AC1, 0,0,0); \
    AC2 = __builtin_amdgcn_mfma_f32_16x16x32_bf16(A3, Whi[2][3], AC2, 0,0,0); \
}

#define K3_GATE(AC0, AC1, AC2, HM, XR, XZ, XN, SLOT, HOOFF, XQ, C) {          \
    const int tw = z ? (127 - (C)) : (C);                                     \
    float rr = sigm(bf2f(XR) + AC0[0] + br);                                  \
    float zg = sigm(bf2f(XZ) + AC1[0] + bz);                                  \
    float nn = tanh_fast(bf2f(XN) + rr * (AC2[0] + bn));                      \
    HM = (1.f - zg) * nn + zg * HM;                                           \
    u16 hb = f2bf(HM);                                                        \
    hist[SLOT][gdim] = hb;                                                    \
    ho[HOOFF + (size_t)tw * 128 + gdim] = hb;                                 \
    int t2 = (C) + 1; if (t2 > 127) t2 = 127;                                 \
    XR = XQ[((size_t)(t2 * 3 + 0) * 128 + gdim) * 8];                         \
    XZ = XQ[((size_t)(t2 * 3 + 1) * 128 + gdim) * 8];                         \
    XN = XQ[((size_t)(t2 * 3 + 2) * 128 + gdim) * 8];                         \
}

__global__ __launch_bounds__(512)
void k3_gru(const u16* __restrict__ xp2,      // [2][128][3][128][8] bf16
            const float* __restrict__ whf, const float* __restrict__ bhf,
            const float* __restrict__ whb, const float* __restrict__ bhb,
            u16* __restrict__ hout)           // [2][8][128][128] bf16
{
    const int z   = blockIdx.x >> 2;
    const int bp  = blockIdx.x & 3;           // batches 2bp (A), 2bp+1 (B)
    const int tid = threadIdx.x;
    const int w   = tid >> 6;
    const int l   = tid & 63;
    const int nr  = l & 15;
    const int kb  = (l >> 4) * 8;
    const int gdim = w * 16 + (l & 15);       // gate hidden dim (valid l<16)

    __shared__ __align__(16) u16 hist[2][128];   // [batch][hidden] 512 B

    const float* W  = z ? whb : whf;
    const float* bh = z ? bhb : bhf;

    // W_hh B-frags (bf16) in VGPRs: wave w owns n-tiles {w, w+8, w+16}
    bf16x8 Whi[3][4];
    #pragma unroll
    for (int g = 0; g < 3; g++) {
        #pragma unroll
        for (int kt = 0; kt < 4; kt++) {
            const float* src = W + (size_t)(g * 128 + w * 16 + nr) * 128 + kt * 32 + kb;
            float4 w0 = *(const float4*)src;
            float4 w1 = *(const float4*)(src + 4);
            bf16x8 hi;
            hi[0] = (short)f2bf(w0.x); hi[1] = (short)f2bf(w0.y);
            hi[2] = (short)f2bf(w0.z); hi[3] = (short)f2bf(w0.w);
            hi[4] = (short)f2bf(w1.x); hi[5] = (short)f2bf(w1.y);
            hi[6] = (short)f2bf(w1.z); hi[7] = (short)f2bf(w1.w);
            Whi[g][kt] = hi;
        }
    }

    float br = 0.f, bz = 0.f, bn = 0.f;
    float hmA = 0.f, hmB = 0.f;
    const u16* xqA = xp2 + (size_t)z * 393216 + 2 * bp;   // batch A (+0)
    const u16* xqB = xqA + 1;                              // batch B (+1)
    u16* ho = hout + (size_t)z * 131072 + (size_t)(2 * bp) * 16384;

    u16 aR = 0, aZ = 0, aN = 0, bR = 0, bZ = 0, bN = 0;
    if (l < 16) {
        br = bh[gdim]; bz = bh[gdim + 128]; bn = bh[gdim + 256];
        aR = xqA[((size_t)0 * 128 + gdim) * 8];
        aZ = xqA[((size_t)1 * 128 + gdim) * 8];
        aN = xqA[((size_t)2 * 128 + gdim) * 8];
        bR = xqB[((size_t)0 * 128 + gdim) * 8];
        bZ = xqB[((size_t)1 * 128 + gdim) * 8];
        bN = xqB[((size_t)2 * 128 + gdim) * 8];
    }
    if (tid < 128) ((unsigned*)hist)[tid] = 0u;    // h = 0 (both batches)
    __syncthreads();

    const f32x4 zero4 = {0.f, 0.f, 0.f, 0.f};
    f32x4 aA0, aA1, aA2, aB0, aB1, aB2;

    for (int c = 0; c < 128; c++) {
        // phase 2c: MFMA A(step c) || gate B(step c-1)
        K3_MFMA(0, aA0, aA1, aA2)
        if (c > 0 && l < 16) {
            K3_GATE(aB0, aB1, aB2, hmB, bR, bZ, bN, 1, 16384, xqB, c - 1)
        }
        STEP_BAR();
        // phase 2c+1: MFMA B(step c) || gate A(step c)
        K3_MFMA(1, aB0, aB1, aB2)
        if (l < 16) {
            K3_GATE(aA0, aA1, aA2, hmA, aR, aZ, aN, 0, 0, xqA, c)
        }
        STEP_BAR();
    }
    // epilogue: gate B(step 127)
    if (l < 16) {
        K3_GATE(aB0, aB1, aB2, hmB, bR, bZ, bN, 1, 16384, xqB, 127)
    }
}

// ---------------------------------------------------------------------------
// K4: MLP head. 1024 blocks = (b,t), 128 threads. (unchanged)
// ---------------------------------------------------------------------------
__global__ __launch_bounds__(128)
void k4_mlp(const u16* __restrict__ hout,
            const float* __restrict__ w1, const float* __restrict__ b1,
            const float* __restrict__ w2, const float* __restrict__ b2,
            float* __restrict__ out)
{
    const int bq  = blockIdx.x;
    const int tid = threadIdx.x;

    __shared__ __align__(16) float hrow[256];
    __shared__ float hid[50];

    const u16* hf = hout + (size_t)bq * 128;
    const u16* hb = hout + (size_t)8 * 128 * 128 + (size_t)bq * 128;
    hrow[tid]       = bf2f(hf[tid]);
    hrow[128 + tid] = bf2f(hb[tid]);
    __syncthreads();

    if (tid < 50) {
        float a = b1[tid];
        const float* wr = w1 + (size_t)tid * 256;
        for (int k0 = 0; k0 < 256; k0 += 8) {
            float4 wv0 = *(const float4*)&wr[k0];
            float4 wv1 = *(const float4*)&wr[k0 + 4];
            float4 h0  = *(const float4*)&hrow[k0];
            float4 h1  = *(const float4*)&hrow[k0 + 4];
            a += wv0.x * h0.x + wv0.y * h0.y + wv0.z * h0.z + wv0.w * h0.w;
            a += wv1.x * h1.x + wv1.y * h1.y + wv1.z * h1.z + wv1.w * h1.w;
        }
        hid[tid] = fmaxf(a, 0.f);
    }
    __syncthreads();
    if (tid < 64) {
        float a = b2[tid];
        const float* wr = w2 + (size_t)tid * 50;
        for (int k = 0; k < 50; k++) a += wr[k] * hid[k];
        out[(size_t)bq * 64 + tid] = a;
    }
}

// ---------------------------------------------------------------------------
// Workspace (2.4 MB):
//   [0,     512K)  : aout bf16 (K1->K2), reused as hout (K3->K4)
//   [512K,  2.0M)  : xp2 bf16 (K2->K3)
//   [2.0M,  2.375M): Wf bf16 [2][384][256] (K0->K2)
//   [2.375M,+3K)   : Bf f32  [2][384]      (K0->K2)
// ---------------------------------------------------------------------------
extern "C" void kernel_launch(void* const* d_in, const int* in_sizes, int n_in,
                              void* d_out, int out_size, void* d_ws, size_t ws_size,
                              hipStream_t stream)
{
    const float* x    = (const float*)d_in[0];
    const float* ts   = (const float*)d_in[1];
    const float* qy   = (const float*)d_in[2];
    const float* bww  = (const float*)d_in[3];
    const float* cw   = (const float*)d_in[4];
    const float* cb   = (const float*)d_in[5];
    const float* wihf = (const float*)d_in[6];
    const float* whhf = (const float*)d_in[7];
    const float* bihf = (const float*)d_in[8];
    const float* bhhf = (const float*)d_in[9];
    const float* wihb = (const float*)d_in[10];
    const float* whhb = (const float*)d_in[11];
    const float* bihb = (const float*)d_in[12];
    const float* bhhb = (const float*)d_in[13];
    const float* w1   = (const float*)d_in[14];
    const float* b1   = (const float*)d_in[15];
    const float* w2   = (const float*)d_in[16];
    const float* b2   = (const float*)d_in[17];
    float* out = (float*)d_out;

    char* ws = (char*)d_ws;
    u16*   aout = (u16*)ws;                            // 512 KB
    u16*   hout = (u16*)ws;                            // alias (aout dead after K2)
    u16*   xp2  = (u16*)(ws + (512 << 10));            // 1.5 MB
    u16*   Wf   = (u16*)(ws + (2u << 20));             // 384 KB
    float* Bf   = (float*)(ws + (2u << 20) + 384 * 1024);  // 3 KB

    k0_fuse<<<192, 256, 0, stream>>>(wihf, bihf, wihb, bihb, cw, cb, Wf, Bf);
    k1_attn<<<256, 1024, 0, stream>>>(x, ts, qy, bww, aout);
    k2_xp<<<768, 256, 0, stream>>>(aout, Wf, Bf, xp2);
    k3_gru<<<8, 512, 0, stream>>>(xp2, whhf, bhhf, whhb, bhhb, hout);
    k4_mlp<<<1024, 128, 0, stream>>>(hout, w1, b1, w2, b2, out);
}

// Round 13
// 147.701 us; speedup vs baseline: 1.1278x; 1.1278x over previous
//
#include <hip/hip_runtime.h>

typedef unsigned short u16;
typedef __attribute__((ext_vector_type(8))) short bf16x8;
typedef __attribute__((ext_vector_type(4))) float f32x4;

#define LOG2E 1.4426950408889634f

__device__ __forceinline__ float bf2f(u16 v) {
    union { unsigned u; float f; } x; x.u = ((unsigned)v) << 16; return x.f;
}
__device__ __forceinline__ u16 f2bf(float f) {
    union { float f; unsigned u; } x; x.f = f;
    unsigned u = x.u;
    u += 0x7FFFu + ((u >> 16) & 1u);   // round-to-nearest-even
    return (u16)(u >> 16);
}
__device__ __forceinline__ float sigm(float x) {
    return __builtin_amdgcn_rcpf(1.f + __builtin_amdgcn_exp2f(-x * LOG2E));
}
__device__ __forceinline__ float tanh_fast(float y) {
    float e = __builtin_amdgcn_exp2f(y * (2.f * LOG2E));
    return 1.f - 2.f * __builtin_amdgcn_rcpf(e + 1.f);   // saturates to +-1 safely
}
// raw barrier: LDS visibility only, NO vmem drain
#define STEP_BAR() asm volatile("s_waitcnt lgkmcnt(0)\ns_barrier" ::: "memory")

// ---------------------------------------------------------------------------
// K0: fold cross projection into GRU input weights. (unchanged)
// ---------------------------------------------------------------------------
__global__ __launch_bounds__(256)
void k0_fuse(const float* __restrict__ wihf, const float* __restrict__ bihf,
             const float* __restrict__ wihb, const float* __restrict__ bihb,
             const float* __restrict__ cw, const float* __restrict__ cb,
             u16* __restrict__ Wf, float* __restrict__ Bf)
{
    const int z  = blockIdx.x / 96;
    const int n0 = (blockIdx.x % 96) * 4;
    const int j  = threadIdx.x;
    const float* W   = z ? wihb : wihf;
    const float* bih = z ? bihb : bihf;

    __shared__ float red[256];

    float a0 = 0.f, a1 = 0.f, a2 = 0.f, a3 = 0.f;
    for (int k = 0; k < 256; k++) {
        float cv = cw[(size_t)k * 256 + j];
        a0 += W[(size_t)(n0 + 0) * 256 + k] * cv;
        a1 += W[(size_t)(n0 + 1) * 256 + k] * cv;
        a2 += W[(size_t)(n0 + 2) * 256 + k] * cv;
        a3 += W[(size_t)(n0 + 3) * 256 + k] * cv;
    }
    u16* wout = Wf + ((size_t)z * 384 + n0) * 256 + j;
    wout[0]   = f2bf(a0);
    wout[256] = f2bf(a1);
    wout[512] = f2bf(a2);
    wout[768] = f2bf(a3);

    float cbv = cb[j];
    #pragma unroll
    for (int i = 0; i < 4; i++) {
        red[j] = W[(size_t)(n0 + i) * 256 + j] * cbv;
        __syncthreads();
        if (j < 64) red[j] += red[j + 64] + red[j + 128] + red[j + 192];
        __syncthreads();
        if (j == 0) {
            float s = 0.f;
            for (int t = 0; t < 64; t++) s += red[t];
            Bf[z * 384 + n0 + i] = s + bih[n0 + i];
        }
        __syncthreads();
    }
}

// ---------------------------------------------------------------------------
// K1: time-kernel attention, zero-LDS main loop. (unchanged)
// ---------------------------------------------------------------------------
__global__ __launch_bounds__(1024)
void k1_attn(const float* __restrict__ x, const float* __restrict__ ts,
             const float* __restrict__ qy, const float* __restrict__ bww,
             u16* __restrict__ aout)
{
    const int b   = blockIdx.x >> 5;
    const int q0  = (blockIdx.x & 31) * 4;
    const int tid = threadIdx.x;
    const int d   = tid & 255;
    const int sh  = (tid >> 8) & 1;
    const int qp  = tid >> 9;
    const int dm  = 128 + (d & 127);

    __shared__ float red[4][512];

    float w  = bww[d];
    float kk = log1pf(expf(w)) * LOG2E;
    float qv0 = qy[q0 + qp * 2], qv1 = qy[q0 + qp * 2 + 1];
    float A0 = -kk * qv0 * qv0, B0 = 2.f * kk * qv0;
    float A1 = -kk * qv1 * qv1, B1 = 2.f * kk * qv1;
    float C  = -kk;

    const float* xb = x + (size_t)b * 512 * 256;
    const float* tb = ts + b * 512;

    float n0 = 0.f, n1 = 0.f, d0 = 0.f, d1 = 0.f;
    const int s0 = sh * 256;
    #pragma unroll 4
    for (int s = s0; s < s0 + 256; s++) {
        float xv = xb[(size_t)s * 256 + d];
        float mv = xb[(size_t)s * 256 + dm];
        float t  = tb[s];
        float ct  = C * t;
        float mxv = mv * xv;
        float p0 = __builtin_amdgcn_exp2f(A0 + t * (B0 + ct));
        float p1 = __builtin_amdgcn_exp2f(A1 + t * (B1 + ct));
        n0 += p0 * mxv;  d0 += p0 * mv;
        n1 += p1 * mxv;  d1 += p1 * mv;
    }

    if (sh == 1) {
        int u = qp * 256 + d;
        red[0][u] = n0; red[1][u] = n1; red[2][u] = d0; red[3][u] = d1;
    }
    __syncthreads();
    if (sh == 0) {
        int u = qp * 256 + d;
        n0 += red[0][u]; n1 += red[1][u]; d0 += red[2][u]; d1 += red[3][u];
        float r0 = n0 / fmaxf(d0, 1e-30f);
        float r1 = n1 / fmaxf(d1, 1e-30f);
        aout[(size_t)(b * 128 + q0 + qp * 2 + 0) * 256 + d] = f2bf(r0);
        aout[(size_t)(b * 128 + q0 + qp * 2 + 1) * 256 + d] = f2bf(r1);
    }
}

// ---------------------------------------------------------------------------
// K2: xp2 = aout @ Wf^T + Bf via MFMA. (unchanged)
// ---------------------------------------------------------------------------
__global__ __launch_bounds__(256)
void k2_xp(const u16* __restrict__ aout,
           const u16* __restrict__ Wf, const float* __restrict__ Bf,
           u16* __restrict__ xp2)    // [2][128][3][128][8] bf16
{
    const int wid  = threadIdx.x >> 6;
    const int lane = threadIdx.x & 63;
    int gw = blockIdx.x * 4 + wid;
    int z  = (gw >= 1536) ? 1 : 0;
    int t  = gw - z * 1536;
    int rt = t / 24, nt = t - rt * 24;
    int r0 = rt * 16, n0 = nt * 16;

    const u16*   W  = Wf + (size_t)z * 384 * 256;
    const float* Bv = Bf + z * 384;

    const u16* arow = aout + (size_t)(r0 + (lane & 15)) * 256 + (lane >> 4) * 8;
    const u16* brow = W    + (size_t)(n0 + (lane & 15)) * 256 + (lane >> 4) * 8;

    f32x4 acc = {0.f, 0.f, 0.f, 0.f};
    #pragma unroll
    for (int k = 0; k < 8; k++) {
        bf16x8 a     = *(const bf16x8*)(arow + k * 32);
        bf16x8 bfrag = *(const bf16x8*)(brow + k * 32);
        acc = __builtin_amdgcn_mfma_f32_16x16x32_bf16(a, bfrag, acc, 0, 0, 0);
    }
    int col   = n0 + (lane & 15);
    int rbase = r0 + (lane >> 4) * 4;
    float bias = Bv[col];
    int g  = col >> 7;
    int dv = col & 127;
    u16* xpz = xp2 + (size_t)z * 393216;
    #pragma unroll
    for (int i = 0; i < 4; i++) {
        int r  = rbase + i;
        int bb = r >> 7;
        int tt = r & 127;
        int tau = z ? (127 - tt) : tt;
        xpz[((size_t)(tau * 3 + g) * 128 + dv) * 8 + bb] = f2bf(acc[i] + bias);
    }
}

// ---------------------------------------------------------------------------
// K3: bidirectional GRU, round-13 layout.
// 4 blocks = (dir z, batch-quad qd), 256 thr (4 waves). Four batches packed
// at A-rows {0,4,8,12} -> C rows 4b land in acc[0] of lane-group b, so ALL
// 64 lanes run exactly one gate chain per owned (r,z,n) triple (2 triples).
// Per step per block: 16 ds_read_b128 (vs 32 in r11 -> halves LDS-pipe
// serialization), 4-wave barrier (vs 8), 24 MFMA issues/wave on a private
// SIMD. hist 2-slot ring, stride 160 u16 (2-way bank alias only).
// ---------------------------------------------------------------------------
__global__ __launch_bounds__(256)
void k3_gru(const u16* __restrict__ xp2,      // [2][128][3][128][8] bf16
            const float* __restrict__ whf, const float* __restrict__ bhf,
            const float* __restrict__ whb, const float* __restrict__ bhb,
            u16* __restrict__ hout)           // [2][8][128][128] bf16
{
    const int z   = blockIdx.x >> 1;
    const int qd  = blockIdx.x & 1;           // batches qd*4 .. qd*4+3
    const int tid = threadIdx.x;
    const int w   = tid >> 6;                 // wave 0..3
    const int l   = tid & 63;
    const int nr  = l & 15;
    const int kb  = (l >> 4) * 8;
    const int b   = l >> 4;                   // gate batch 0..3
    const int d0  = w * 32 + nr;              // gate dim, triple 0
    const int d1  = d0 + 16;                  // gate dim, triple 1

    __shared__ __align__(16) u16 hist[2][4][160];   // 2.5 KB, padded stride

    const float* W  = z ? whb : whf;
    const float* bh = z ? bhb : bhf;

    // W_hh B-frags (bf16) in VGPRs: wave w owns n-rows
    //   N = g*128 + w*32 + ti*16 + nr   for g in {r,z,n}, ti in {0,1}
    bf16x8 Wh[3][2][4];
    #pragma unroll
    for (int g = 0; g < 3; g++) {
        #pragma unroll
        for (int ti = 0; ti < 2; ti++) {
            #pragma unroll
            for (int kt = 0; kt < 4; kt++) {
                const float* src = W + (size_t)(g * 128 + w * 32 + ti * 16 + nr) * 128 + kt * 32 + kb;
                float4 w0 = *(const float4*)src;
                float4 w1 = *(const float4*)(src + 4);
                bf16x8 hi;
                hi[0] = (short)f2bf(w0.x); hi[1] = (short)f2bf(w0.y);
                hi[2] = (short)f2bf(w0.z); hi[3] = (short)f2bf(w0.w);
                hi[4] = (short)f2bf(w1.x); hi[5] = (short)f2bf(w1.y);
                hi[6] = (short)f2bf(w1.z); hi[7] = (short)f2bf(w1.w);
                Wh[g][ti][kt] = hi;
            }
        }
    }

    const float br0 = bh[d0], bz0 = bh[d0 + 128], bn0 = bh[d0 + 256];
    const float br1 = bh[d1], bz1 = bh[d1 + 128], bn1 = bh[d1 + 256];
    float hm0 = 0.f, hm1 = 0.f;

    const u16* xq = xp2 + (size_t)z * 393216 + qd * 4 + b;
    u16* ho = hout + (size_t)z * 131072 + (size_t)(qd * 4 + b) * 16384;

    u16 xR0 = xq[((size_t)(0 * 3 + 0) * 128 + d0) * 8];
    u16 xZ0 = xq[((size_t)(0 * 3 + 1) * 128 + d0) * 8];
    u16 xN0 = xq[((size_t)(0 * 3 + 2) * 128 + d0) * 8];
    u16 xR1 = xq[((size_t)(0 * 3 + 0) * 128 + d1) * 8];
    u16 xZ1 = xq[((size_t)(0 * 3 + 1) * 128 + d1) * 8];
    u16 xN1 = xq[((size_t)(0 * 3 + 2) * 128 + d1) * 8];

    for (int i = tid; i < 640; i += 256) ((unsigned*)hist)[i] = 0u;   // both slots
    __syncthreads();

    const f32x4 z4 = {0.f, 0.f, 0.f, 0.f};

    for (int c = 0; c < 128; c++) {
        const int rs  = (c + 1) & 1;
        const int wsl = c & 1;

        // A-frags: lanes with row in {0,4,8,12} read batch row>>2; others zero
        bf16x8 A0 = {0,0,0,0,0,0,0,0}, A1 = A0, A2 = A0, A3 = A0;
        if ((nr & 3) == 0) {
            const u16* hb_ = &hist[rs][nr >> 2][kb];
            A0 = *(const bf16x8*)&hb_[0];
            A1 = *(const bf16x8*)&hb_[32];
            A2 = *(const bf16x8*)&hb_[64];
            A3 = *(const bf16x8*)&hb_[96];
        }

        f32x4 aR0 = z4, aR1 = z4, aZ0 = z4, aZ1 = z4, aN0 = z4, aN1 = z4;
        aR0 = __builtin_amdgcn_mfma_f32_16x16x32_bf16(A0, Wh[0][0][0], aR0, 0,0,0);
        aR1 = __builtin_amdgcn_mfma_f32_16x16x32_bf16(A0, Wh[0][1][0], aR1, 0,0,0);
        aZ0 = __builtin_amdgcn_mfma_f32_16x16x32_bf16(A0, Wh[1][0][0], aZ0, 0,0,0);
        aZ1 = __builtin_amdgcn_mfma_f32_16x16x32_bf16(A0, Wh[1][1][0], aZ1, 0,0,0);
        aN0 = __builtin_amdgcn_mfma_f32_16x16x32_bf16(A0, Wh[2][0][0], aN0, 0,0,0);
        aN1 = __builtin_amdgcn_mfma_f32_16x16x32_bf16(A0, Wh[2][1][0], aN1, 0,0,0);
        aR0 = __builtin_amdgcn_mfma_f32_16x16x32_bf16(A1, Wh[0][0][1], aR0, 0,0,0);
        aR1 = __builtin_amdgcn_mfma_f32_16x16x32_bf16(A1, Wh[0][1][1], aR1, 0,0,0);
        aZ0 = __builtin_amdgcn_mfma_f32_16x16x32_bf16(A1, Wh[1][0][1], aZ0, 0,0,0);
        aZ1 = __builtin_amdgcn_mfma_f32_16x16x32_bf16(A1, Wh[1][1][1], aZ1, 0,0,0);
        aN0 = __builtin_amdgcn_mfma_f32_16x16x32_bf16(A1, Wh[2][0][1], aN0, 0,0,0);
        aN1 = __builtin_amdgcn_mfma_f32_16x16x32_bf16(A1, Wh[2][1][1], aN1, 0,0,0);
        aR0 = __builtin_amdgcn_mfma_f32_16x16x32_bf16(A2, Wh[0][0][2], aR0, 0,0,0);
        aR1 = __builtin_amdgcn_mfma_f32_16x16x32_bf16(A2, Wh[0][1][2], aR1, 0,0,0);
        aZ0 = __builtin_amdgcn_mfma_f32_16x16x32_bf16(A2, Wh[1][0][2], aZ0, 0,0,0);
        aZ1 = __builtin_amdgcn_mfma_f32_16x16x32_bf16(A2, Wh[1][1][2], aZ1, 0,0,0);
        aN0 = __builtin_amdgcn_mfma_f32_16x16x32_bf16(A2, Wh[2][0][2], aN0, 0,0,0);
        aN1 = __builtin_amdgcn_mfma_f32_16x16x32_bf16(A2, Wh[2][1][2], aN1, 0,0,0);
        aR0 = __builtin_amdgcn_mfma_f32_16x16x32_bf16(A3, Wh[0][0][3], aR0, 0,0,0);
        aR1 = __builtin_amdgcn_mfma_f32_16x16x32_bf16(A3, Wh[0][1][3], aR1, 0,0,0);
        aZ0 = __builtin_amdgcn_mfma_f32_16x16x32_bf16(A3, Wh[1][0][3], aZ0, 0,0,0);
        aZ1 = __builtin_amdgcn_mfma_f32_16x16x32_bf16(A3, Wh[1][1][3], aZ1, 0,0,0);
        aN0 = __builtin_amdgcn_mfma_f32_16x16x32_bf16(A3, Wh[2][0][3], aN0, 0,0,0);
        aN1 = __builtin_amdgcn_mfma_f32_16x16x32_bf16(A3, Wh[2][1][3], aN1, 0,0,0);

        // gate: every lane, batch b = l>>4, dims d0 and d1 (acc[0] = C row 4b)
        const int tw = z ? (127 - c) : c;
        {
            float rr = sigm(bf2f(xR0) + aR0[0] + br0);
            float zg = sigm(bf2f(xZ0) + aZ0[0] + bz0);
            float nn = tanh_fast(bf2f(xN0) + rr * (aN0[0] + bn0));
            hm0 = (1.f - zg) * nn + zg * hm0;
            u16 hb_ = f2bf(hm0);
            hist[wsl][b][d0] = hb_;
            ho[(size_t)tw * 128 + d0] = hb_;
        }
        {
            float rr = sigm(bf2f(xR1) + aR1[0] + br1);
            float zg = sigm(bf2f(xZ1) + aZ1[0] + bz1);
            float nn = tanh_fast(bf2f(xN1) + rr * (aN1[0] + bn1));
            hm1 = (1.f - zg) * nn + zg * hm1;
            u16 hb_ = f2bf(hm1);
            hist[wsl][b][d1] = hb_;
            ho[(size_t)tw * 128 + d1] = hb_;
        }
        int t2 = c + 1; if (t2 > 127) t2 = 127;
        xR0 = xq[((size_t)(t2 * 3 + 0) * 128 + d0) * 8];
        xZ0 = xq[((size_t)(t2 * 3 + 1) * 128 + d0) * 8];
        xN0 = xq[((size_t)(t2 * 3 + 2) * 128 + d0) * 8];
        xR1 = xq[((size_t)(t2 * 3 + 0) * 128 + d1) * 8];
        xZ1 = xq[((size_t)(t2 * 3 + 1) * 128 + d1) * 8];
        xN1 = xq[((size_t)(t2 * 3 + 2) * 128 + d1) * 8];

        STEP_BAR();
    }
}

// ---------------------------------------------------------------------------
// K4: MLP head. 1024 blocks = (b,t), 128 threads. (unchanged)
// ---------------------------------------------------------------------------
__global__ __launch_bounds__(128)
void k4_mlp(const u16* __restrict__ hout,
            const float* __restrict__ w1, const float* __restrict__ b1,
            const float* __restrict__ w2, const float* __restrict__ b2,
            float* __restrict__ out)
{
    const int bq  = blockIdx.x;
    const int tid = threadIdx.x;

    __shared__ __align__(16) float hrow[256];
    __shared__ float hid[50];

    const u16* hf = hout + (size_t)bq * 128;
    const u16* hb = hout + (size_t)8 * 128 * 128 + (size_t)bq * 128;
    hrow[tid]       = bf2f(hf[tid]);
    hrow[128 + tid] = bf2f(hb[tid]);
    __syncthreads();

    if (tid < 50) {
        float a = b1[tid];
        const float* wr = w1 + (size_t)tid * 256;
        for (int k0 = 0; k0 < 256; k0 += 8) {
            float4 wv0 = *(const float4*)&wr[k0];
            float4 wv1 = *(const float4*)&wr[k0 + 4];
            float4 h0  = *(const float4*)&hrow[k0];
            float4 h1  = *(const float4*)&hrow[k0 + 4];
            a += wv0.x * h0.x + wv0.y * h0.y + wv0.z * h0.z + wv0.w * h0.w;
            a += wv1.x * h1.x + wv1.y * h1.y + wv1.z * h1.z + wv1.w * h1.w;
        }
        hid[tid] = fmaxf(a, 0.f);
    }
    __syncthreads();
    if (tid < 64) {
        float a = b2[tid];
        const float* wr = w2 + (size_t)tid * 50;
        for (int k = 0; k < 50; k++) a += wr[k] * hid[k];
        out[(size_t)bq * 64 + tid] = a;
    }
}

// ---------------------------------------------------------------------------
// Workspace (2.4 MB):
//   [0,     512K)  : aout bf16 (K1->K2), reused as hout (K3->K4)
//   [512K,  2.0M)  : xp2 bf16 (K2->K3)
//   [2.0M,  2.375M): Wf bf16 [2][384][256] (K0->K2)
//   [2.375M,+3K)   : Bf f32  [2][384]      (K0->K2)
// ---------------------------------------------------------------------------
extern "C" void kernel_launch(void* const* d_in, const int* in_sizes, int n_in,
                              void* d_out, int out_size, void* d_ws, size_t ws_size,
                              hipStream_t stream)
{
    const float* x    = (const float*)d_in[0];
    const float* ts   = (const float*)d_in[1];
    const float* qy   = (const float*)d_in[2];
    const float* bww  = (const float*)d_in[3];
    const float* cw   = (const float*)d_in[4];
    const float* cb   = (const float*)d_in[5];
    const float* wihf = (const float*)d_in[6];
    const float* whhf = (const float*)d_in[7];
    const float* bihf = (const float*)d_in[8];
    const float* bhhf = (const float*)d_in[9];
    const float* wihb = (const float*)d_in[10];
    const float* whhb = (const float*)d_in[11];
    const float* bihb = (const float*)d_in[12];
    const float* bhhb = (const float*)d_in[13];
    const float* w1   = (const float*)d_in[14];
    const float* b1   = (const float*)d_in[15];
    const float* w2   = (const float*)d_in[16];
    const float* b2   = (const float*)d_in[17];
    float* out = (float*)d_out;

    char* ws = (char*)d_ws;
    u16*   aout = (u16*)ws;                            // 512 KB
    u16*   hout = (u16*)ws;                            // alias (aout dead after K2)
    u16*   xp2  = (u16*)(ws + (512 << 10));            // 1.5 MB
    u16*   Wf   = (u16*)(ws + (2u << 20));             // 384 KB
    float* Bf   = (float*)(ws + (2u << 20) + 384 * 1024);  // 3 KB

    k0_fuse<<<192, 256, 0, stream>>>(wihf, bihf, wihb, bihb, cw, cb, Wf, Bf);
    k1_attn<<<256, 1024, 0, stream>>>(x, ts, qy, bww, aout);
    k2_xp<<<768, 256, 0, stream>>>(aout, Wf, Bf, xp2);
    k3_gru<<<4, 256, 0, stream>>>(xp2, whhf, bhhf, whhb, bhhb, hout);
    k4_mlp<<<1024, 128, 0, stream>>>(hout, w1, b1, w2, b2, out);
}

// Round 14
// 131.488 us; speedup vs baseline: 1.2669x; 1.1233x over previous
//
#include <hip/hip_runtime.h>

typedef unsigned short u16;
typedef __attribute__((ext_vector_type(8))) short bf16x8;
typedef __attribute__((ext_vector_type(4))) float f32x4;
typedef __attribute__((ext_vector_type(4))) unsigned short u16x4;
typedef __attribute__((ext_vector_type(8))) unsigned short u16x8;

#define LOG2E 1.4426950408889634f

__device__ __forceinline__ float bf2f(u16 v) {
    union { unsigned u; float f; } x; x.u = ((unsigned)v) << 16; return x.f;
}
__device__ __forceinline__ u16 f2bf(float f) {
    union { float f; unsigned u; } x; x.f = f;
    unsigned u = x.u;
    u += 0x7FFFu + ((u >> 16) & 1u);   // round-to-nearest-even
    return (u16)(u >> 16);
}
__device__ __forceinline__ float sigm(float x) {
    return __builtin_amdgcn_rcpf(1.f + __builtin_amdgcn_exp2f(-x * LOG2E));
}
__device__ __forceinline__ float tanh_fast(float y) {
    float e = __builtin_amdgcn_exp2f(y * (2.f * LOG2E));
    return 1.f - 2.f * __builtin_amdgcn_rcpf(e + 1.f);   // saturates to +-1 safely
}
// raw barrier: LDS visibility only, NO vmem drain
#define STEP_BAR() asm volatile("s_waitcnt lgkmcnt(0)\ns_barrier" ::: "memory")

// ---------------------------------------------------------------------------
// K0: fold cross projection into GRU input weights. (unchanged)
// ---------------------------------------------------------------------------
__global__ __launch_bounds__(256)
void k0_fuse(const float* __restrict__ wihf, const float* __restrict__ bihf,
             const float* __restrict__ wihb, const float* __restrict__ bihb,
             const float* __restrict__ cw, const float* __restrict__ cb,
             u16* __restrict__ Wf, float* __restrict__ Bf)
{
    const int z  = blockIdx.x / 96;
    const int n0 = (blockIdx.x % 96) * 4;
    const int j  = threadIdx.x;
    const float* W   = z ? wihb : wihf;
    const float* bih = z ? bihb : bihf;

    __shared__ float red[256];

    float a0 = 0.f, a1 = 0.f, a2 = 0.f, a3 = 0.f;
    for (int k = 0; k < 256; k++) {
        float cv = cw[(size_t)k * 256 + j];
        a0 += W[(size_t)(n0 + 0) * 256 + k] * cv;
        a1 += W[(size_t)(n0 + 1) * 256 + k] * cv;
        a2 += W[(size_t)(n0 + 2) * 256 + k] * cv;
        a3 += W[(size_t)(n0 + 3) * 256 + k] * cv;
    }
    u16* wout = Wf + ((size_t)z * 384 + n0) * 256 + j;
    wout[0]   = f2bf(a0);
    wout[256] = f2bf(a1);
    wout[512] = f2bf(a2);
    wout[768] = f2bf(a3);

    float cbv = cb[j];
    #pragma unroll
    for (int i = 0; i < 4; i++) {
        red[j] = W[(size_t)(n0 + i) * 256 + j] * cbv;
        __syncthreads();
        if (j < 64) red[j] += red[j + 64] + red[j + 128] + red[j + 192];
        __syncthreads();
        if (j == 0) {
            float s = 0.f;
            for (int t = 0; t < 64; t++) s += red[t];
            Bf[z * 384 + n0 + i] = s + bih[n0 + i];
        }
        __syncthreads();
    }
}

// ---------------------------------------------------------------------------
// K1: time-kernel attention, zero-LDS main loop. (unchanged)
// ---------------------------------------------------------------------------
__global__ __launch_bounds__(1024)
void k1_attn(const float* __restrict__ x, const float* __restrict__ ts,
             const float* __restrict__ qy, const float* __restrict__ bww,
             u16* __restrict__ aout)
{
    const int b   = blockIdx.x >> 5;
    const int q0  = (blockIdx.x & 31) * 4;
    const int tid = threadIdx.x;
    const int d   = tid & 255;
    const int sh  = (tid >> 8) & 1;
    const int qp  = tid >> 9;
    const int dm  = 128 + (d & 127);

    __shared__ float red[4][512];

    float w  = bww[d];
    float kk = log1pf(expf(w)) * LOG2E;
    float qv0 = qy[q0 + qp * 2], qv1 = qy[q0 + qp * 2 + 1];
    float A0 = -kk * qv0 * qv0, B0 = 2.f * kk * qv0;
    float A1 = -kk * qv1 * qv1, B1 = 2.f * kk * qv1;
    float C  = -kk;

    const float* xb = x + (size_t)b * 512 * 256;
    const float* tb = ts + b * 512;

    float n0 = 0.f, n1 = 0.f, d0 = 0.f, d1 = 0.f;
    const int s0 = sh * 256;
    #pragma unroll 4
    for (int s = s0; s < s0 + 256; s++) {
        float xv = xb[(size_t)s * 256 + d];
        float mv = xb[(size_t)s * 256 + dm];
        float t  = tb[s];
        float ct  = C * t;
        float mxv = mv * xv;
        float p0 = __builtin_amdgcn_exp2f(A0 + t * (B0 + ct));
        float p1 = __builtin_amdgcn_exp2f(A1 + t * (B1 + ct));
        n0 += p0 * mxv;  d0 += p0 * mv;
        n1 += p1 * mxv;  d1 += p1 * mv;
    }

    if (sh == 1) {
        int u = qp * 256 + d;
        red[0][u] = n0; red[1][u] = n1; red[2][u] = d0; red[3][u] = d1;
    }
    __syncthreads();
    if (sh == 0) {
        int u = qp * 256 + d;
        n0 += red[0][u]; n1 += red[1][u]; d0 += red[2][u]; d1 += red[3][u];
        float r0 = n0 / fmaxf(d0, 1e-30f);
        float r1 = n1 / fmaxf(d1, 1e-30f);
        aout[(size_t)(b * 128 + q0 + qp * 2 + 0) * 256 + d] = f2bf(r0);
        aout[(size_t)(b * 128 + q0 + qp * 2 + 1) * 256 + d] = f2bf(r1);
    }
}

// ---------------------------------------------------------------------------
// K2: xp3 = aout @ Wf^T + Bf via MFMA.
// NEW layout: XP3[z][g][dim][b][tau] bf16, tau = (z ? 127-t : t) -- tau
// innermost so K3 can load 8 steps as one ushort8. The 4 output rows of a
// wave-tile span 4 consecutive taus -> packed into one 8B store (reversed
// element order for z=1).
// ---------------------------------------------------------------------------
__global__ __launch_bounds__(256)
void k2_xp(const u16* __restrict__ aout,
           const u16* __restrict__ Wf, const float* __restrict__ Bf,
           u16* __restrict__ xp3)    // [2][3][128][8][128] bf16
{
    const int wid  = threadIdx.x >> 6;
    const int lane = threadIdx.x & 63;
    int gw = blockIdx.x * 4 + wid;
    int z  = (gw >= 1536) ? 1 : 0;
    int t  = gw - z * 1536;
    int rt = t / 24, nt = t - rt * 24;
    int r0 = rt * 16, n0 = nt * 16;

    const u16*   W  = Wf + (size_t)z * 384 * 256;
    const float* Bv = Bf + z * 384;

    const u16* arow = aout + (size_t)(r0 + (lane & 15)) * 256 + (lane >> 4) * 8;
    const u16* brow = W    + (size_t)(n0 + (lane & 15)) * 256 + (lane >> 4) * 8;

    f32x4 acc = {0.f, 0.f, 0.f, 0.f};
    #pragma unroll
    for (int k = 0; k < 8; k++) {
        bf16x8 a     = *(const bf16x8*)(arow + k * 32);
        bf16x8 bfrag = *(const bf16x8*)(brow + k * 32);
        acc = __builtin_amdgcn_mfma_f32_16x16x32_bf16(a, bfrag, acc, 0, 0, 0);
    }
    int col   = n0 + (lane & 15);
    int rbase = r0 + (lane >> 4) * 4;
    float bias = Bv[col];
    int g   = col >> 7;
    int dv  = col & 127;
    int bb  = rbase >> 7;
    int tt0 = rbase & 127;                    // multiple of 4, rows stay in-batch
    u16* xpz = xp3 + (size_t)z * 393216;
    size_t base = ((size_t)(g * 128 + dv) * 8 + bb) * 128;
    u16 v0 = f2bf(acc[0] + bias), v1 = f2bf(acc[1] + bias);
    u16 v2 = f2bf(acc[2] + bias), v3 = f2bf(acc[3] + bias);
    if (z == 0) {
        u16x4 pv = {v0, v1, v2, v3};
        *(u16x4*)&xpz[base + tt0] = pv;           // taus tt0..tt0+3
    } else {
        u16x4 pv = {v3, v2, v1, v0};
        *(u16x4*)&xpz[base + 124 - tt0] = pv;     // taus 124-tt0..127-tt0
    }
}

// ---------------------------------------------------------------------------
// K3: bidirectional GRU -- round-11 structure (8 blocks=(z,bp) x 8 waves,
// 12 MFMA/wave/step, 32-lane gate, one raw barrier/step) + CHUNKED XP
// PREFETCH: gate lanes load 8 steps of (r,z,n) as three ushort8 one full
// chunk ahead (xp3 tau-innermost layout), so the ~900cy HBM/L2 latency of
// the old per-step 2B loads leaves the critical path entirely.
// ---------------------------------------------------------------------------
__global__ __launch_bounds__(512)
void k3_gru(const u16* __restrict__ xp3,      // [2][3][128][8][128] bf16
            const float* __restrict__ whf, const float* __restrict__ bhf,
            const float* __restrict__ whb, const float* __restrict__ bhb,
            u16* __restrict__ hout)           // [2][8][128][128] bf16
{
    const int z   = blockIdx.x >> 2;
    const int bp  = blockIdx.x & 3;           // batches 2bp, 2bp+1
    const int tid = threadIdx.x;
    const int w   = tid >> 6;
    const int l   = tid & 63;
    const int nr  = l & 15;
    const int kb  = (l >> 4) * 8;
    const int gm   = l >> 4;                  // gate batch (valid l<32)
    const int gdim = w * 16 + (l & 15);       // gate hidden dim (valid l<32)

    __shared__ __align__(16) u16 hist[2][2][128];   // [slot][m][hidden] 1 KB

    const float* W  = z ? whb : whf;
    const float* bh = z ? bhb : bhf;

    // W_hh B-frags (bf16) in VGPRs: wave w owns n-tiles {w, w+8, w+16}
    bf16x8 Whi[3][4];
    #pragma unroll
    for (int g = 0; g < 3; g++) {
        #pragma unroll
        for (int kt = 0; kt < 4; kt++) {
            const float* src = W + (size_t)(g * 128 + w * 16 + nr) * 128 + kt * 32 + kb;
            float4 w0 = *(const float4*)src;
            float4 w1 = *(const float4*)(src + 4);
            bf16x8 hi;
            hi[0] = (short)f2bf(w0.x); hi[1] = (short)f2bf(w0.y);
            hi[2] = (short)f2bf(w0.z); hi[3] = (short)f2bf(w0.w);
            hi[4] = (short)f2bf(w1.x); hi[5] = (short)f2bf(w1.y);
            hi[6] = (short)f2bf(w1.z); hi[7] = (short)f2bf(w1.w);
            Whi[g][kt] = hi;
        }
    }

    float br = 0.f, bz = 0.f, bn = 0.f;
    float hm = 0.f;
    const u16* xq = xp3 + (size_t)z * 393216;
    u16* ho = hout + (size_t)z * 131072 + (size_t)(2 * bp) * 16384;

    // chunked prefetch bases (element index; tau appended)
    size_t bR = 0, bZ = 0, bN = 0;
    u16x8 cR = {0,0,0,0,0,0,0,0}, cZ = cR, cN = cR;   // current chunk
    u16x8 nR = cR, nZ = cR, nN = cR;                  // next chunk
    if (l < 32) {
        br = bh[gdim]; bz = bh[gdim + 128]; bn = bh[gdim + 256];
        bR = ((size_t)(0 * 128 + gdim) * 8 + 2 * bp + gm) * 128;
        bZ = ((size_t)(1 * 128 + gdim) * 8 + 2 * bp + gm) * 128;
        bN = ((size_t)(2 * 128 + gdim) * 8 + 2 * bp + gm) * 128;
        cR = *(const u16x8*)&xq[bR];      cZ = *(const u16x8*)&xq[bZ];      cN = *(const u16x8*)&xq[bN];
        nR = *(const u16x8*)&xq[bR + 8];  nZ = *(const u16x8*)&xq[bZ + 8];  nN = *(const u16x8*)&xq[bN + 8];
    }
    if (tid < 256) ((unsigned*)hist)[tid] = 0u;    // h = 0 (both slots)
    __syncthreads();

    const f32x4 z4 = {0.f, 0.f, 0.f, 0.f};

    for (int ch = 0; ch < 16; ch++) {
        #pragma unroll
        for (int s = 0; s < 8; s++) {
            const int c = ch * 8 + s;
            const int rslot = (c + 1) & 1, wslot = c & 1;

            bf16x8 A0 = {0,0,0,0,0,0,0,0}, A1 = A0, A2 = A0, A3 = A0;
            if ((nr & 3) == 0 && nr < 8) {   // rows 0,4 hold batches 0,1
                const u16* hb_ = &hist[rslot][nr >> 2][0];
                A0 = *(const bf16x8*)&hb_[kb];
                A1 = *(const bf16x8*)&hb_[32 + kb];
                A2 = *(const bf16x8*)&hb_[64 + kb];
                A3 = *(const bf16x8*)&hb_[96 + kb];
            }
            f32x4 a0 = z4, a1 = z4, a2 = z4;
            a0 = __builtin_amdgcn_mfma_f32_16x16x32_bf16(A0, Whi[0][0], a0, 0,0,0);
            a1 = __builtin_amdgcn_mfma_f32_16x16x32_bf16(A0, Whi[1][0], a1, 0,0,0);
            a2 = __builtin_amdgcn_mfma_f32_16x16x32_bf16(A0, Whi[2][0], a2, 0,0,0);
            a0 = __builtin_amdgcn_mfma_f32_16x16x32_bf16(A1, Whi[0][1], a0, 0,0,0);
            a1 = __builtin_amdgcn_mfma_f32_16x16x32_bf16(A1, Whi[1][1], a1, 0,0,0);
            a2 = __builtin_amdgcn_mfma_f32_16x16x32_bf16(A1, Whi[2][1], a2, 0,0,0);
            a0 = __builtin_amdgcn_mfma_f32_16x16x32_bf16(A2, Whi[0][2], a0, 0,0,0);
            a1 = __builtin_amdgcn_mfma_f32_16x16x32_bf16(A2, Whi[1][2], a1, 0,0,0);
            a2 = __builtin_amdgcn_mfma_f32_16x16x32_bf16(A2, Whi[2][2], a2, 0,0,0);
            a0 = __builtin_amdgcn_mfma_f32_16x16x32_bf16(A3, Whi[0][3], a0, 0,0,0);
            a1 = __builtin_amdgcn_mfma_f32_16x16x32_bf16(A3, Whi[1][3], a1, 0,0,0);
            a2 = __builtin_amdgcn_mfma_f32_16x16x32_bf16(A3, Whi[2][3], a2, 0,0,0);

            if (l < 32) {
                const int tw = z ? (127 - c) : c;
                float rr = sigm(bf2f((u16)cR[s]) + a0[0] + br);
                float zg = sigm(bf2f((u16)cZ[s]) + a1[0] + bz);
                float nn = tanh_fast(bf2f((u16)cN[s]) + rr * (a2[0] + bn));
                hm = (1.f - zg) * nn + zg * hm;
                u16 hb_ = f2bf(hm);
                hist[wslot][gm][gdim] = hb_;
                ho[(size_t)gm * 16384 + (size_t)tw * 128 + gdim] = hb_;
            }
            STEP_BAR();
        }
        // chunk boundary: rotate and issue loads for chunk ch+2
        if (l < 32) {
            cR = nR; cZ = nZ; cN = nN;
            if (ch < 14) {
                const size_t o = (size_t)(ch + 2) * 8;
                nR = *(const u16x8*)&xq[bR + o];
                nZ = *(const u16x8*)&xq[bZ + o];
                nN = *(const u16x8*)&xq[bN + o];
            }
        }
    }
}

// ---------------------------------------------------------------------------
// K4: MLP head. 1024 blocks = (b,t), 128 threads. (unchanged)
// ---------------------------------------------------------------------------
__global__ __launch_bounds__(128)
void k4_mlp(const u16* __restrict__ hout,
            const float* __restrict__ w1, const float* __restrict__ b1,
            const float* __restrict__ w2, const float* __restrict__ b2,
            float* __restrict__ out)
{
    const int bq  = blockIdx.x;
    const int tid = threadIdx.x;

    __shared__ __align__(16) float hrow[256];
    __shared__ float hid[50];

    const u16* hf = hout + (size_t)bq * 128;
    const u16* hb = hout + (size_t)8 * 128 * 128 + (size_t)bq * 128;
    hrow[tid]       = bf2f(hf[tid]);
    hrow[128 + tid] = bf2f(hb[tid]);
    __syncthreads();

    if (tid < 50) {
        float a = b1[tid];
        const float* wr = w1 + (size_t)tid * 256;
        for (int k0 = 0; k0 < 256; k0 += 8) {
            float4 wv0 = *(const float4*)&wr[k0];
            float4 wv1 = *(const float4*)&wr[k0 + 4];
            float4 h0  = *(const float4*)&hrow[k0];
            float4 h1  = *(const float4*)&hrow[k0 + 4];
            a += wv0.x * h0.x + wv0.y * h0.y + wv0.z * h0.z + wv0.w * h0.w;
            a += wv1.x * h1.x + wv1.y * h1.y + wv1.z * h1.z + wv1.w * h1.w;
        }
        hid[tid] = fmaxf(a, 0.f);
    }
    __syncthreads();
    if (tid < 64) {
        float a = b2[tid];
        const float* wr = w2 + (size_t)tid * 50;
        for (int k = 0; k < 50; k++) a += wr[k] * hid[k];
        out[(size_t)bq * 64 + tid] = a;
    }
}

// ---------------------------------------------------------------------------
// Workspace (2.4 MB):
//   [0,     512K)  : aout bf16 (K1->K2), reused as hout (K3->K4)
//   [512K,  2.0M)  : xp3 bf16 (K2->K3, tau-innermost layout)
//   [2.0M,  2.375M): Wf bf16 [2][384][256] (K0->K2)
//   [2.375M,+3K)   : Bf f32  [2][384]      (K0->K2)
// ---------------------------------------------------------------------------
extern "C" void kernel_launch(void* const* d_in, const int* in_sizes, int n_in,
                              void* d_out, int out_size, void* d_ws, size_t ws_size,
                              hipStream_t stream)
{
    const float* x    = (const float*)d_in[0];
    const float* ts   = (const float*)d_in[1];
    const float* qy   = (const float*)d_in[2];
    const float* bww  = (const float*)d_in[3];
    const float* cw   = (const float*)d_in[4];
    const float* cb   = (const float*)d_in[5];
    const float* wihf = (const float*)d_in[6];
    const float* whhf = (const float*)d_in[7];
    const float* bihf = (const float*)d_in[8];
    const float* bhhf = (const float*)d_in[9];
    const float* wihb = (const float*)d_in[10];
    const float* whhb = (const float*)d_in[11];
    const float* bihb = (const float*)d_in[12];
    const float* bhhb = (const float*)d_in[13];
    const float* w1   = (const float*)d_in[14];
    const float* b1   = (const float*)d_in[15];
    const float* w2   = (const float*)d_in[16];
    const float* b2   = (const float*)d_in[17];
    float* out = (float*)d_out;

    char* ws = (char*)d_ws;
    u16*   aout = (u16*)ws;                            // 512 KB
    u16*   hout = (u16*)ws;                            // alias (aout dead after K2)
    u16*   xp3  = (u16*)(ws + (512 << 10));            // 1.5 MB
    u16*   Wf   = (u16*)(ws + (2u << 20));             // 384 KB
    float* Bf   = (float*)(ws + (2u << 20) + 384 * 1024);  // 3 KB

    k0_fuse<<<192, 256, 0, stream>>>(wihf, bihf, wihb, bihb, cw, cb, Wf, Bf);
    k1_attn<<<256, 1024, 0, stream>>>(x, ts, qy, bww, aout);
    k2_xp<<<768, 256, 0, stream>>>(aout, Wf, Bf, xp3);
    k3_gru<<<8, 512, 0, stream>>>(xp3, whhf, bhhf, whhb, bhhb, hout);
    k4_mlp<<<1024, 128, 0, stream>>>(hout, w1, b1, w2, b2, out);
}

// Round 15
// 122.213 us; speedup vs baseline: 1.3630x; 1.0759x over previous
//
#include <hip/hip_runtime.h>

typedef unsigned short u16;
typedef __attribute__((ext_vector_type(8))) short bf16x8;
typedef __attribute__((ext_vector_type(4))) float f32x4;
typedef __attribute__((ext_vector_type(4))) unsigned short u16x4;
typedef __attribute__((ext_vector_type(8))) unsigned short u16x8;

#define LOG2E 1.4426950408889634f

__device__ __forceinline__ float bf2f(u16 v) {
    union { unsigned u; float f; } x; x.u = ((unsigned)v) << 16; return x.f;
}
__device__ __forceinline__ u16 f2bf(float f) {
    union { float f; unsigned u; } x; x.f = f;
    unsigned u = x.u;
    u += 0x7FFFu + ((u >> 16) & 1u);   // round-to-nearest-even
    return (u16)(u >> 16);
}
__device__ __forceinline__ float sigm(float x) {
    return __builtin_amdgcn_rcpf(1.f + __builtin_amdgcn_exp2f(-x * LOG2E));
}
__device__ __forceinline__ float tanh_fast(float y) {
    float e = __builtin_amdgcn_exp2f(y * (2.f * LOG2E));
    return 1.f - 2.f * __builtin_amdgcn_rcpf(e + 1.f);   // saturates to +-1 safely
}
// raw barrier: LDS visibility only, NO vmem drain
#define STEP_BAR() asm volatile("s_waitcnt lgkmcnt(0)\ns_barrier" ::: "memory")

// ---------------------------------------------------------------------------
// K0: fold cross projection into GRU input weights. (unchanged)
// ---------------------------------------------------------------------------
__global__ __launch_bounds__(256)
void k0_fuse(const float* __restrict__ wihf, const float* __restrict__ bihf,
             const float* __restrict__ wihb, const float* __restrict__ bihb,
             const float* __restrict__ cw, const float* __restrict__ cb,
             u16* __restrict__ Wf, float* __restrict__ Bf)
{
    const int z  = blockIdx.x / 96;
    const int n0 = (blockIdx.x % 96) * 4;
    const int j  = threadIdx.x;
    const float* W   = z ? wihb : wihf;
    const float* bih = z ? bihb : bihf;

    __shared__ float red[256];

    float a0 = 0.f, a1 = 0.f, a2 = 0.f, a3 = 0.f;
    for (int k = 0; k < 256; k++) {
        float cv = cw[(size_t)k * 256 + j];
        a0 += W[(size_t)(n0 + 0) * 256 + k] * cv;
        a1 += W[(size_t)(n0 + 1) * 256 + k] * cv;
        a2 += W[(size_t)(n0 + 2) * 256 + k] * cv;
        a3 += W[(size_t)(n0 + 3) * 256 + k] * cv;
    }
    u16* wout = Wf + ((size_t)z * 384 + n0) * 256 + j;
    wout[0]   = f2bf(a0);
    wout[256] = f2bf(a1);
    wout[512] = f2bf(a2);
    wout[768] = f2bf(a3);

    float cbv = cb[j];
    #pragma unroll
    for (int i = 0; i < 4; i++) {
        red[j] = W[(size_t)(n0 + i) * 256 + j] * cbv;
        __syncthreads();
        if (j < 64) red[j] += red[j + 64] + red[j + 128] + red[j + 192];
        __syncthreads();
        if (j == 0) {
            float s = 0.f;
            for (int t = 0; t < 64; t++) s += red[t];
            Bf[z * 384 + n0 + i] = s + bih[n0 + i];
        }
        __syncthreads();
    }
}

// ---------------------------------------------------------------------------
// K1: time-kernel attention, zero-LDS main loop. (unchanged)
// ---------------------------------------------------------------------------
__global__ __launch_bounds__(1024)
void k1_attn(const float* __restrict__ x, const float* __restrict__ ts,
             const float* __restrict__ qy, const float* __restrict__ bww,
             u16* __restrict__ aout)
{
    const int b   = blockIdx.x >> 5;
    const int q0  = (blockIdx.x & 31) * 4;
    const int tid = threadIdx.x;
    const int d   = tid & 255;
    const int sh  = (tid >> 8) & 1;
    const int qp  = tid >> 9;
    const int dm  = 128 + (d & 127);

    __shared__ float red[4][512];

    float w  = bww[d];
    float kk = log1pf(expf(w)) * LOG2E;
    float qv0 = qy[q0 + qp * 2], qv1 = qy[q0 + qp * 2 + 1];
    float A0 = -kk * qv0 * qv0, B0 = 2.f * kk * qv0;
    float A1 = -kk * qv1 * qv1, B1 = 2.f * kk * qv1;
    float C  = -kk;

    const float* xb = x + (size_t)b * 512 * 256;
    const float* tb = ts + b * 512;

    float n0 = 0.f, n1 = 0.f, d0 = 0.f, d1 = 0.f;
    const int s0 = sh * 256;
    #pragma unroll 4
    for (int s = s0; s < s0 + 256; s++) {
        float xv = xb[(size_t)s * 256 + d];
        float mv = xb[(size_t)s * 256 + dm];
        float t  = tb[s];
        float ct  = C * t;
        float mxv = mv * xv;
        float p0 = __builtin_amdgcn_exp2f(A0 + t * (B0 + ct));
        float p1 = __builtin_amdgcn_exp2f(A1 + t * (B1 + ct));
        n0 += p0 * mxv;  d0 += p0 * mv;
        n1 += p1 * mxv;  d1 += p1 * mv;
    }

    if (sh == 1) {
        int u = qp * 256 + d;
        red[0][u] = n0; red[1][u] = n1; red[2][u] = d0; red[3][u] = d1;
    }
    __syncthreads();
    if (sh == 0) {
        int u = qp * 256 + d;
        n0 += red[0][u]; n1 += red[1][u]; d0 += red[2][u]; d1 += red[3][u];
        float r0 = n0 / fmaxf(d0, 1e-30f);
        float r1 = n1 / fmaxf(d1, 1e-30f);
        aout[(size_t)(b * 128 + q0 + qp * 2 + 0) * 256 + d] = f2bf(r0);
        aout[(size_t)(b * 128 + q0 + qp * 2 + 1) * 256 + d] = f2bf(r1);
    }
}

// ---------------------------------------------------------------------------
// K2: xp3 = aout @ Wf^T + Bf via MFMA, XP3[z][g][dim][b][tau] layout.
// (unchanged)
// ---------------------------------------------------------------------------
__global__ __launch_bounds__(256)
void k2_xp(const u16* __restrict__ aout,
           const u16* __restrict__ Wf, const float* __restrict__ Bf,
           u16* __restrict__ xp3)    // [2][3][128][8][128] bf16
{
    const int wid  = threadIdx.x >> 6;
    const int lane = threadIdx.x & 63;
    int gw = blockIdx.x * 4 + wid;
    int z  = (gw >= 1536) ? 1 : 0;
    int t  = gw - z * 1536;
    int rt = t / 24, nt = t - rt * 24;
    int r0 = rt * 16, n0 = nt * 16;

    const u16*   W  = Wf + (size_t)z * 384 * 256;
    const float* Bv = Bf + z * 384;

    const u16* arow = aout + (size_t)(r0 + (lane & 15)) * 256 + (lane >> 4) * 8;
    const u16* brow = W    + (size_t)(n0 + (lane & 15)) * 256 + (lane >> 4) * 8;

    f32x4 acc = {0.f, 0.f, 0.f, 0.f};
    #pragma unroll
    for (int k = 0; k < 8; k++) {
        bf16x8 a     = *(const bf16x8*)(arow + k * 32);
        bf16x8 bfrag = *(const bf16x8*)(brow + k * 32);
        acc = __builtin_amdgcn_mfma_f32_16x16x32_bf16(a, bfrag, acc, 0, 0, 0);
    }
    int col   = n0 + (lane & 15);
    int rbase = r0 + (lane >> 4) * 4;
    float bias = Bv[col];
    int g   = col >> 7;
    int dv  = col & 127;
    int bb  = rbase >> 7;
    int tt0 = rbase & 127;
    u16* xpz = xp3 + (size_t)z * 393216;
    size_t base = ((size_t)(g * 128 + dv) * 8 + bb) * 128;
    u16 v0 = f2bf(acc[0] + bias), v1 = f2bf(acc[1] + bias);
    u16 v2 = f2bf(acc[2] + bias), v3 = f2bf(acc[3] + bias);
    if (z == 0) {
        u16x4 pv = {v0, v1, v2, v3};
        *(u16x4*)&xpz[base + tt0] = pv;
    } else {
        u16x4 pv = {v3, v2, v1, v0};
        *(u16x4*)&xpz[base + 124 - tt0] = pv;
    }
}

// ---------------------------------------------------------------------------
// K3: bidirectional GRU, round-15: ONE recurrence per block.
// 16 blocks = (z, b), 512 thr (8 waves). Per step (r12's validated ~980cy
// phase, now one per step instead of two serial):
//   - A-frags: broadcast ds_read of h (all lanes; 16-lane groups share addr)
//   - 12 MFMA/wave (wave w owns n-tile triple {w, w+8, w+16})
//   - gate on lanes <16 (16 dims/wave x 8 waves = 128 dims)
//   - one raw barrier
// hist = 2-slot x 128 bf16 ring. xp via r14's chunked ushort8 prefetch.
// ---------------------------------------------------------------------------
__global__ __launch_bounds__(512)
void k3_gru(const u16* __restrict__ xp3,      // [2][3][128][8][128] bf16
            const float* __restrict__ whf, const float* __restrict__ bhf,
            const float* __restrict__ whb, const float* __restrict__ bhb,
            u16* __restrict__ hout)           // [2][8][128][128] bf16
{
    const int z   = blockIdx.x >> 3;
    const int b   = blockIdx.x & 7;           // batch
    const int tid = threadIdx.x;
    const int w   = tid >> 6;
    const int l   = tid & 63;
    const int nr  = l & 15;
    const int kb  = (l >> 4) * 8;
    const int gdim = w * 16 + (l & 15);       // gate hidden dim (valid l<16)

    __shared__ __align__(16) u16 hist[2][128];   // [slot][hidden] 512 B

    const float* W  = z ? whb : whf;
    const float* bh = z ? bhb : bhf;

    // W_hh B-frags (bf16) in VGPRs: wave w owns n-tiles {w, w+8, w+16}
    bf16x8 Whi[3][4];
    #pragma unroll
    for (int g = 0; g < 3; g++) {
        #pragma unroll
        for (int kt = 0; kt < 4; kt++) {
            const float* src = W + (size_t)(g * 128 + w * 16 + nr) * 128 + kt * 32 + kb;
            float4 w0 = *(const float4*)src;
            float4 w1 = *(const float4*)(src + 4);
            bf16x8 hi;
            hi[0] = (short)f2bf(w0.x); hi[1] = (short)f2bf(w0.y);
            hi[2] = (short)f2bf(w0.z); hi[3] = (short)f2bf(w0.w);
            hi[4] = (short)f2bf(w1.x); hi[5] = (short)f2bf(w1.y);
            hi[6] = (short)f2bf(w1.z); hi[7] = (short)f2bf(w1.w);
            Whi[g][kt] = hi;
        }
    }

    float br = 0.f, bz = 0.f, bn = 0.f;
    float hm = 0.f;
    const u16* xq = xp3 + (size_t)z * 393216;
    u16* ho = hout + (size_t)z * 131072 + (size_t)b * 16384;

    // chunked xp prefetch (gate lanes only)
    size_t bR = 0, bZ = 0, bN = 0;
    u16x8 cR = {0,0,0,0,0,0,0,0}, cZ = cR, cN = cR;   // current chunk
    u16x8 nR = cR, nZ = cR, nN = cR;                  // next chunk
    if (l < 16) {
        br = bh[gdim]; bz = bh[gdim + 128]; bn = bh[gdim + 256];
        bR = ((size_t)(0 * 128 + gdim) * 8 + b) * 128;
        bZ = ((size_t)(1 * 128 + gdim) * 8 + b) * 128;
        bN = ((size_t)(2 * 128 + gdim) * 8 + b) * 128;
        cR = *(const u16x8*)&xq[bR];      cZ = *(const u16x8*)&xq[bZ];      cN = *(const u16x8*)&xq[bN];
        nR = *(const u16x8*)&xq[bR + 8];  nZ = *(const u16x8*)&xq[bZ + 8];  nN = *(const u16x8*)&xq[bN + 8];
    }
    if (tid < 128) ((unsigned*)hist)[tid] = 0u;    // h = 0 (both slots)
    __syncthreads();

    const f32x4 z4 = {0.f, 0.f, 0.f, 0.f};

    for (int ch = 0; ch < 16; ch++) {
        #pragma unroll
        for (int s = 0; s < 8; s++) {
            const int c = ch * 8 + s;
            const int rslot = (c + 1) & 1, wslot = c & 1;

            // broadcast A-frag read: every lane reads h[kb..kb+7] chunks
            // (lanes 16j..16j+15 share an address -> LDS broadcast)
            const u16* hb_ = &hist[rslot][kb];
            bf16x8 A0 = *(const bf16x8*)&hb_[0];
            bf16x8 A1 = *(const bf16x8*)&hb_[32];
            bf16x8 A2 = *(const bf16x8*)&hb_[64];
            bf16x8 A3 = *(const bf16x8*)&hb_[96];

            f32x4 a0 = z4, a1 = z4, a2 = z4;
            a0 = __builtin_amdgcn_mfma_f32_16x16x32_bf16(A0, Whi[0][0], a0, 0,0,0);
            a1 = __builtin_amdgcn_mfma_f32_16x16x32_bf16(A0, Whi[1][0], a1, 0,0,0);
            a2 = __builtin_amdgcn_mfma_f32_16x16x32_bf16(A0, Whi[2][0], a2, 0,0,0);
            a0 = __builtin_amdgcn_mfma_f32_16x16x32_bf16(A1, Whi[0][1], a0, 0,0,0);
            a1 = __builtin_amdgcn_mfma_f32_16x16x32_bf16(A1, Whi[1][1], a1, 0,0,0);
            a2 = __builtin_amdgcn_mfma_f32_16x16x32_bf16(A1, Whi[2][1], a2, 0,0,0);
            a0 = __builtin_amdgcn_mfma_f32_16x16x32_bf16(A2, Whi[0][2], a0, 0,0,0);
            a1 = __builtin_amdgcn_mfma_f32_16x16x32_bf16(A2, Whi[1][2], a1, 0,0,0);
            a2 = __builtin_amdgcn_mfma_f32_16x16x32_bf16(A2, Whi[2][2], a2, 0,0,0);
            a0 = __builtin_amdgcn_mfma_f32_16x16x32_bf16(A3, Whi[0][3], a0, 0,0,0);
            a1 = __builtin_amdgcn_mfma_f32_16x16x32_bf16(A3, Whi[1][3], a1, 0,0,0);
            a2 = __builtin_amdgcn_mfma_f32_16x16x32_bf16(A3, Whi[2][3], a2, 0,0,0);

            if (l < 16) {
                const int tw = z ? (127 - c) : c;
                float rr = sigm(bf2f((u16)cR[s]) + a0[0] + br);
                float zg = sigm(bf2f((u16)cZ[s]) + a1[0] + bz);
                float nn = tanh_fast(bf2f((u16)cN[s]) + rr * (a2[0] + bn));
                hm = (1.f - zg) * nn + zg * hm;
                u16 hb2 = f2bf(hm);
                hist[wslot][gdim] = hb2;
                ho[(size_t)tw * 128 + gdim] = hb2;
            }
            STEP_BAR();
        }
        // chunk boundary: rotate and issue loads for chunk ch+2
        if (l < 16) {
            cR = nR; cZ = nZ; cN = nN;
            if (ch < 14) {
                const size_t o = (size_t)(ch + 2) * 8;
                nR = *(const u16x8*)&xq[bR + o];
                nZ = *(const u16x8*)&xq[bZ + o];
                nN = *(const u16x8*)&xq[bN + o];
            }
        }
    }
}

// ---------------------------------------------------------------------------
// K4: MLP head. 1024 blocks = (b,t), 128 threads. (unchanged)
// ---------------------------------------------------------------------------
__global__ __launch_bounds__(128)
void k4_mlp(const u16* __restrict__ hout,
            const float* __restrict__ w1, const float* __restrict__ b1,
            const float* __restrict__ w2, const float* __restrict__ b2,
            float* __restrict__ out)
{
    const int bq  = blockIdx.x;
    const int tid = threadIdx.x;

    __shared__ __align__(16) float hrow[256];
    __shared__ float hid[50];

    const u16* hf = hout + (size_t)bq * 128;
    const u16* hb = hout + (size_t)8 * 128 * 128 + (size_t)bq * 128;
    hrow[tid]       = bf2f(hf[tid]);
    hrow[128 + tid] = bf2f(hb[tid]);
    __syncthreads();

    if (tid < 50) {
        float a = b1[tid];
        const float* wr = w1 + (size_t)tid * 256;
        for (int k0 = 0; k0 < 256; k0 += 8) {
            float4 wv0 = *(const float4*)&wr[k0];
            float4 wv1 = *(const float4*)&wr[k0 + 4];
            float4 h0  = *(const float4*)&hrow[k0];
            float4 h1  = *(const float4*)&hrow[k0 + 4];
            a += wv0.x * h0.x + wv0.y * h0.y + wv0.z * h0.z + wv0.w * h0.w;
            a += wv1.x * h1.x + wv1.y * h1.y + wv1.z * h1.z + wv1.w * h1.w;
        }
        hid[tid] = fmaxf(a, 0.f);
    }
    __syncthreads();
    if (tid < 64) {
        float a = b2[tid];
        const float* wr = w2 + (size_t)tid * 50;
        for (int k = 0; k < 50; k++) a += wr[k] * hid[k];
        out[(size_t)bq * 64 + tid] = a;
    }
}

// ---------------------------------------------------------------------------
// Workspace (2.4 MB):
//   [0,     512K)  : aout bf16 (K1->K2), reused as hout (K3->K4)
//   [512K,  2.0M)  : xp3 bf16 (K2->K3, tau-innermost layout)
//   [2.0M,  2.375M): Wf bf16 [2][384][256] (K0->K2)
//   [2.375M,+3K)   : Bf f32  [2][384]      (K0->K2)
// ---------------------------------------------------------------------------
extern "C" void kernel_launch(void* const* d_in, const int* in_sizes, int n_in,
                              void* d_out, int out_size, void* d_ws, size_t ws_size,
                              hipStream_t stream)
{
    const float* x    = (const float*)d_in[0];
    const float* ts   = (const float*)d_in[1];
    const float* qy   = (const float*)d_in[2];
    const float* bww  = (const float*)d_in[3];
    const float* cw   = (const float*)d_in[4];
    const float* cb   = (const float*)d_in[5];
    const float* wihf = (const float*)d_in[6];
    const float* whhf = (const float*)d_in[7];
    const float* bihf = (const float*)d_in[8];
    const float* bhhf = (const float*)d_in[9];
    const float* wihb = (const float*)d_in[10];
    const float* whhb = (const float*)d_in[11];
    const float* bihb = (const float*)d_in[12];
    const float* bhhb = (const float*)d_in[13];
    const float* w1   = (const float*)d_in[14];
    const float* b1   = (const float*)d_in[15];
    const float* w2   = (const float*)d_in[16];
    const float* b2   = (const float*)d_in[17];
    float* out = (float*)d_out;

    char* ws = (char*)d_ws;
    u16*   aout = (u16*)ws;                            // 512 KB
    u16*   hout = (u16*)ws;                            // alias (aout dead after K2)
    u16*   xp3  = (u16*)(ws + (512 << 10));            // 1.5 MB
    u16*   Wf   = (u16*)(ws + (2u << 20));             // 384 KB
    float* Bf   = (float*)(ws + (2u << 20) + 384 * 1024);  // 3 KB

    k0_fuse<<<192, 256, 0, stream>>>(wihf, bihf, wihb, bihb, cw, cb, Wf, Bf);
    k1_attn<<<256, 1024, 0, stream>>>(x, ts, qy, bww, aout);
    k2_xp<<<768, 256, 0, stream>>>(aout, Wf, Bf, xp3);
    k3_gru<<<16, 512, 0, stream>>>(xp3, whhf, bhhf, whhb, bhhb, hout);
    k4_mlp<<<1024, 128, 0, stream>>>(hout, w1, b1, w2, b2, out);
}

// Round 16
// 118.032 us; speedup vs baseline: 1.4113x; 1.0354x over previous
//
#include <hip/hip_runtime.h>

typedef unsigned short u16;
typedef __attribute__((ext_vector_type(8))) short bf16x8;
typedef __attribute__((ext_vector_type(4))) float f32x4;
typedef __attribute__((ext_vector_type(4))) unsigned short u16x4;
typedef __attribute__((ext_vector_type(8))) unsigned short u16x8;

#define LOG2E 1.4426950408889634f

__device__ __forceinline__ float bf2f(u16 v) {
    union { unsigned u; float f; } x; x.u = ((unsigned)v) << 16; return x.f;
}
__device__ __forceinline__ u16 f2bf(float f) {
    union { float f; unsigned u; } x; x.f = f;
    unsigned u = x.u;
    u += 0x7FFFu + ((u >> 16) & 1u);   // round-to-nearest-even
    return (u16)(u >> 16);
}
__device__ __forceinline__ float sigm(float x) {
    return __builtin_amdgcn_rcpf(1.f + __builtin_amdgcn_exp2f(-x * LOG2E));
}
__device__ __forceinline__ float tanh_fast(float y) {
    float e = __builtin_amdgcn_exp2f(y * (2.f * LOG2E));
    return 1.f - 2.f * __builtin_amdgcn_rcpf(e + 1.f);   // saturates to +-1 safely
}
// raw barrier: LDS visibility only, NO vmem drain
#define STEP_BAR() asm volatile("s_waitcnt lgkmcnt(0)\ns_barrier" ::: "memory")

// ---------------------------------------------------------------------------
// K0: fold cross projection into GRU input weights AND fold the constant
// upper-half attention output (aout[:,:,128:256] == 1.0 exactly -- the
// attended "values" there ARE the mask channel, so masked-softmax weights
// sum to 1) into the bias:
//   Bf2[z][n] = bih[n] + sum_k wih[n][k]*cb[k] + sum_{j>=128} bf16(Wf[n][j])
// ---------------------------------------------------------------------------
__global__ __launch_bounds__(256)
void k0_fuse(const float* __restrict__ wihf, const float* __restrict__ bihf,
             const float* __restrict__ wihb, const float* __restrict__ bihb,
             const float* __restrict__ cw, const float* __restrict__ cb,
             u16* __restrict__ Wf, float* __restrict__ Bf)
{
    const int z  = blockIdx.x / 96;
    const int n0 = (blockIdx.x % 96) * 4;
    const int j  = threadIdx.x;
    const float* W   = z ? wihb : wihf;
    const float* bih = z ? bihb : bihf;

    __shared__ float red[256];

    float av[4] = {0.f, 0.f, 0.f, 0.f};
    for (int k = 0; k < 256; k++) {
        float cv = cw[(size_t)k * 256 + j];
        av[0] += W[(size_t)(n0 + 0) * 256 + k] * cv;
        av[1] += W[(size_t)(n0 + 1) * 256 + k] * cv;
        av[2] += W[(size_t)(n0 + 2) * 256 + k] * cv;
        av[3] += W[(size_t)(n0 + 3) * 256 + k] * cv;
    }
    u16 wb16[4];
    u16* wout = Wf + ((size_t)z * 384 + n0) * 256 + j;
    #pragma unroll
    for (int i = 0; i < 4; i++) {
        wb16[i] = f2bf(av[i]);
        wout[i * 256] = wb16[i];
    }

    float cbv = cb[j];
    #pragma unroll
    for (int i = 0; i < 4; i++) {
        float up = (j >= 128) ? bf2f(wb16[i]) : 0.f;   // upper-half fold (aout==1)
        red[j] = W[(size_t)(n0 + i) * 256 + j] * cbv + up;
        __syncthreads();
        if (j < 64) red[j] += red[j + 64] + red[j + 128] + red[j + 192];
        __syncthreads();
        if (j == 0) {
            float s = 0.f;
            for (int t = 0; t < 64; t++) s += red[t];
            Bf[z * 384 + n0 + i] = s + bih[n0 + i];
        }
        __syncthreads();
    }
}

// ---------------------------------------------------------------------------
// K1: time-kernel attention, LOWER HALF ONLY (d<128; upper half == 1.0 and
// is folded into Bf by K0). Zero-LDS main loop; half the exp2 of round 15.
// grid: 256 blocks = (b, qt of 4 q); 1024 thr = (qq 0-3, sh 0-1, d 0-127).
// ---------------------------------------------------------------------------
__global__ __launch_bounds__(1024)
void k1_attn(const float* __restrict__ x, const float* __restrict__ ts,
             const float* __restrict__ qy, const float* __restrict__ bww,
             u16* __restrict__ aout)     // [1024][128] bf16
{
    const int b   = blockIdx.x >> 5;
    const int q0  = (blockIdx.x & 31) * 4;
    const int tid = threadIdx.x;
    const int d   = tid & 127;
    const int sh  = (tid >> 7) & 1;
    const int qq  = tid >> 8;

    __shared__ float red[2][4][128];

    float w  = bww[d];
    float kk = log1pf(expf(w)) * LOG2E;     // exp(sc*bw) == exp2(sc*kk)
    float qv = qy[q0 + qq];
    float A  = -kk * qv * qv, B = 2.f * kk * qv, C = -kk;

    const float* xb = x + (size_t)b * 512 * 256;
    const float* tb = ts + b * 512;

    float num = 0.f, den = 0.f;
    const int s0 = sh * 256;
    #pragma unroll 4
    for (int s = s0; s < s0 + 256; s++) {
        float xv = xb[(size_t)s * 256 + d];          // vals*mask
        float mv = xb[(size_t)s * 256 + 128 + d];    // mask in {0,1}
        float t  = tb[s];                            // uniform -> s_load
        float p  = __builtin_amdgcn_exp2f(A + t * (B + C * t));
        num += p * (mv * xv);
        den += p * mv;
    }

    if (sh == 1) {
        red[0][qq][d] = num;
        red[1][qq][d] = den;
    }
    __syncthreads();
    if (sh == 0) {
        num += red[0][qq][d];
        den += red[1][qq][d];
        aout[(size_t)(b * 128 + q0 + qq) * 128 + d] = f2bf(num / fmaxf(den, 1e-30f));
    }
}

// ---------------------------------------------------------------------------
// K2: xp3 = aout @ Wf[:,0:128]^T + Bf2 via MFMA (K=128 -> 4 k-steps).
// XP3[z][g][dim][b][tau] layout, tau = (z ? 127-t : t).
// ---------------------------------------------------------------------------
__global__ __launch_bounds__(256)
void k2_xp(const u16* __restrict__ aout,
           const u16* __restrict__ Wf, const float* __restrict__ Bf,
           u16* __restrict__ xp3)    // [2][3][128][8][128] bf16
{
    const int wid  = threadIdx.x >> 6;
    const int lane = threadIdx.x & 63;
    int gw = blockIdx.x * 4 + wid;
    int z  = (gw >= 1536) ? 1 : 0;
    int t  = gw - z * 1536;
    int rt = t / 24, nt = t - rt * 24;
    int r0 = rt * 16, n0 = nt * 16;

    const u16*   W  = Wf + (size_t)z * 384 * 256;
    const float* Bv = Bf + z * 384;

    const u16* arow = aout + (size_t)(r0 + (lane & 15)) * 128 + (lane >> 4) * 8;
    const u16* brow = W    + (size_t)(n0 + (lane & 15)) * 256 + (lane >> 4) * 8;

    f32x4 acc = {0.f, 0.f, 0.f, 0.f};
    #pragma unroll
    for (int k = 0; k < 4; k++) {
        bf16x8 a     = *(const bf16x8*)(arow + k * 32);
        bf16x8 bfrag = *(const bf16x8*)(brow + k * 32);
        acc = __builtin_amdgcn_mfma_f32_16x16x32_bf16(a, bfrag, acc, 0, 0, 0);
    }
    int col   = n0 + (lane & 15);
    int rbase = r0 + (lane >> 4) * 4;
    float bias = Bv[col];
    int g   = col >> 7;
    int dv  = col & 127;
    int bb  = rbase >> 7;
    int tt0 = rbase & 127;
    u16* xpz = xp3 + (size_t)z * 393216;
    size_t base = ((size_t)(g * 128 + dv) * 8 + bb) * 128;
    u16 v0 = f2bf(acc[0] + bias), v1 = f2bf(acc[1] + bias);
    u16 v2 = f2bf(acc[2] + bias), v3 = f2bf(acc[3] + bias);
    if (z == 0) {
        u16x4 pv = {v0, v1, v2, v3};
        *(u16x4*)&xpz[base + tt0] = pv;
    } else {
        u16x4 pv = {v3, v2, v1, v0};
        *(u16x4*)&xpz[base + 124 - tt0] = pv;
    }
}

// ---------------------------------------------------------------------------
// K3: bidirectional GRU, one recurrence per block (r15 structure) +
// PARALLEL MFMA ACCUMULATORS: 12 independent MFMAs (no 4-deep C-chains);
// gate lanes sum the four acc[0]s with 3 adds per gate -- removes ~3x
// MFMA dependency latency from the serial step.
// 16 blocks = (z, b), 512 thr (8 waves), 1 raw barrier/step.
// ---------------------------------------------------------------------------
__global__ __launch_bounds__(512)
void k3_gru(const u16* __restrict__ xp3,      // [2][3][128][8][128] bf16
            const float* __restrict__ whf, const float* __restrict__ bhf,
            const float* __restrict__ whb, const float* __restrict__ bhb,
            u16* __restrict__ hout)           // [2][8][128][128] bf16
{
    const int z   = blockIdx.x >> 3;
    const int b   = blockIdx.x & 7;           // batch
    const int tid = threadIdx.x;
    const int w   = tid >> 6;
    const int l   = tid & 63;
    const int nr  = l & 15;
    const int kb  = (l >> 4) * 8;
    const int gdim = w * 16 + (l & 15);       // gate hidden dim (valid l<16)

    __shared__ __align__(16) u16 hist[2][128];   // [slot][hidden] 512 B

    const float* W  = z ? whb : whf;
    const float* bh = z ? bhb : bhf;

    // W_hh B-frags (bf16) in VGPRs: wave w owns n-tiles {w, w+8, w+16}
    bf16x8 Whi[3][4];
    #pragma unroll
    for (int g = 0; g < 3; g++) {
        #pragma unroll
        for (int kt = 0; kt < 4; kt++) {
            const float* src = W + (size_t)(g * 128 + w * 16 + nr) * 128 + kt * 32 + kb;
            float4 w0 = *(const float4*)src;
            float4 w1 = *(const float4*)(src + 4);
            bf16x8 hi;
            hi[0] = (short)f2bf(w0.x); hi[1] = (short)f2bf(w0.y);
            hi[2] = (short)f2bf(w0.z); hi[3] = (short)f2bf(w0.w);
            hi[4] = (short)f2bf(w1.x); hi[5] = (short)f2bf(w1.y);
            hi[6] = (short)f2bf(w1.z); hi[7] = (short)f2bf(w1.w);
            Whi[g][kt] = hi;
        }
    }

    float br = 0.f, bz = 0.f, bn = 0.f;
    float hm = 0.f;
    const u16* xq = xp3 + (size_t)z * 393216;
    u16* ho = hout + (size_t)z * 131072 + (size_t)b * 16384;

    // chunked xp prefetch (gate lanes only)
    size_t bR = 0, bZ = 0, bN = 0;
    u16x8 cR = {0,0,0,0,0,0,0,0}, cZ = cR, cN = cR;   // current chunk
    u16x8 nR = cR, nZ = cR, nN = cR;                  // next chunk
    if (l < 16) {
        br = bh[gdim]; bz = bh[gdim + 128]; bn = bh[gdim + 256];
        bR = ((size_t)(0 * 128 + gdim) * 8 + b) * 128;
        bZ = ((size_t)(1 * 128 + gdim) * 8 + b) * 128;
        bN = ((size_t)(2 * 128 + gdim) * 8 + b) * 128;
        cR = *(const u16x8*)&xq[bR];      cZ = *(const u16x8*)&xq[bZ];      cN = *(const u16x8*)&xq[bN];
        nR = *(const u16x8*)&xq[bR + 8];  nZ = *(const u16x8*)&xq[bZ + 8];  nN = *(const u16x8*)&xq[bN + 8];
    }
    if (tid < 128) ((unsigned*)hist)[tid] = 0u;    // h = 0 (both slots)
    __syncthreads();

    const f32x4 z4 = {0.f, 0.f, 0.f, 0.f};

    for (int ch = 0; ch < 16; ch++) {
        #pragma unroll
        for (int s = 0; s < 8; s++) {
            const int c = ch * 8 + s;
            const int rslot = (c + 1) & 1, wslot = c & 1;

            // broadcast A-frag read (16-lane groups share an address)
            const u16* hb_ = &hist[rslot][kb];
            bf16x8 A0 = *(const bf16x8*)&hb_[0];
            bf16x8 A1 = *(const bf16x8*)&hb_[32];
            bf16x8 A2 = *(const bf16x8*)&hb_[64];
            bf16x8 A3 = *(const bf16x8*)&hb_[96];

            // 12 INDEPENDENT MFMAs (parallel accumulators)
            f32x4 r0 = __builtin_amdgcn_mfma_f32_16x16x32_bf16(A0, Whi[0][0], z4, 0,0,0);
            f32x4 z0 = __builtin_amdgcn_mfma_f32_16x16x32_bf16(A0, Whi[1][0], z4, 0,0,0);
            f32x4 n0 = __builtin_amdgcn_mfma_f32_16x16x32_bf16(A0, Whi[2][0], z4, 0,0,0);
            f32x4 r1 = __builtin_amdgcn_mfma_f32_16x16x32_bf16(A1, Whi[0][1], z4, 0,0,0);
            f32x4 z1 = __builtin_amdgcn_mfma_f32_16x16x32_bf16(A1, Whi[1][1], z4, 0,0,0);
            f32x4 n1 = __builtin_amdgcn_mfma_f32_16x16x32_bf16(A1, Whi[2][1], z4, 0,0,0);
            f32x4 r2 = __builtin_amdgcn_mfma_f32_16x16x32_bf16(A2, Whi[0][2], z4, 0,0,0);
            f32x4 z2 = __builtin_amdgcn_mfma_f32_16x16x32_bf16(A2, Whi[1][2], z4, 0,0,0);
            f32x4 n2 = __builtin_amdgcn_mfma_f32_16x16x32_bf16(A2, Whi[2][2], z4, 0,0,0);
            f32x4 r3 = __builtin_amdgcn_mfma_f32_16x16x32_bf16(A3, Whi[0][3], z4, 0,0,0);
            f32x4 z3 = __builtin_amdgcn_mfma_f32_16x16x32_bf16(A3, Whi[1][3], z4, 0,0,0);
            f32x4 n3 = __builtin_amdgcn_mfma_f32_16x16x32_bf16(A3, Whi[2][3], z4, 0,0,0);

            if (l < 16) {
                const int tw = z ? (127 - c) : c;
                float ar = (r0[0] + r1[0]) + (r2[0] + r3[0]);
                float az = (z0[0] + z1[0]) + (z2[0] + z3[0]);
                float an = (n0[0] + n1[0]) + (n2[0] + n3[0]);
                float rr = sigm(bf2f((u16)cR[s]) + ar + br);
                float zg = sigm(bf2f((u16)cZ[s]) + az + bz);
                float nn = tanh_fast(bf2f((u16)cN[s]) + rr * (an + bn));
                hm = (1.f - zg) * nn + zg * hm;
                u16 hb2 = f2bf(hm);
                hist[wslot][gdim] = hb2;
                ho[(size_t)tw * 128 + gdim] = hb2;
            }
            STEP_BAR();
        }
        // chunk boundary: rotate and issue loads for chunk ch+2
        if (l < 16) {
            cR = nR; cZ = nZ; cN = nN;
            if (ch < 14) {
                const size_t o = (size_t)(ch + 2) * 8;
                nR = *(const u16x8*)&xq[bR + o];
                nZ = *(const u16x8*)&xq[bZ + o];
                nN = *(const u16x8*)&xq[bN + o];
            }
        }
    }
}

// ---------------------------------------------------------------------------
// K4: MLP head. 1024 blocks = (b,t), 128 threads. (unchanged)
// ---------------------------------------------------------------------------
__global__ __launch_bounds__(128)
void k4_mlp(const u16* __restrict__ hout,
            const float* __restrict__ w1, const float* __restrict__ b1,
            const float* __restrict__ w2, const float* __restrict__ b2,
            float* __restrict__ out)
{
    const int bq  = blockIdx.x;
    const int tid = threadIdx.x;

    __shared__ __align__(16) float hrow[256];
    __shared__ float hid[50];

    const u16* hf = hout + (size_t)bq * 128;
    const u16* hb = hout + (size_t)8 * 128 * 128 + (size_t)bq * 128;
    hrow[tid]       = bf2f(hf[tid]);
    hrow[128 + tid] = bf2f(hb[tid]);
    __syncthreads();

    if (tid < 50) {
        float a = b1[tid];
        const float* wr = w1 + (size_t)tid * 256;
        for (int k0 = 0; k0 < 256; k0 += 8) {
            float4 wv0 = *(const float4*)&wr[k0];
            float4 wv1 = *(const float4*)&wr[k0 + 4];
            float4 h0  = *(const float4*)&hrow[k0];
            float4 h1  = *(const float4*)&hrow[k0 + 4];
            a += wv0.x * h0.x + wv0.y * h0.y + wv0.z * h0.z + wv0.w * h0.w;
            a += wv1.x * h1.x + wv1.y * h1.y + wv1.z * h1.z + wv1.w * h1.w;
        }
        hid[tid] = fmaxf(a, 0.f);
    }
    __syncthreads();
    if (tid < 64) {
        float a = b2[tid];
        const float* wr = w2 + (size_t)tid * 50;
        for (int k = 0; k < 50; k++) a += wr[k] * hid[k];
        out[(size_t)bq * 64 + tid] = a;
    }
}

// ---------------------------------------------------------------------------
// Workspace (2.4 MB):
//   [0,     512K)  : aout bf16 [1024][128] (K1->K2), reused as hout (K3->K4)
//   [512K,  2.0M)  : xp3 bf16 (K2->K3, tau-innermost layout)
//   [2.0M,  2.375M): Wf bf16 [2][384][256] (K0->K2)
//   [2.375M,+3K)   : Bf f32  [2][384]      (K0->K2, upper-half folded)
// ---------------------------------------------------------------------------
extern "C" void kernel_launch(void* const* d_in, const int* in_sizes, int n_in,
                              void* d_out, int out_size, void* d_ws, size_t ws_size,
                              hipStream_t stream)
{
    const float* x    = (const float*)d_in[0];
    const float* ts   = (const float*)d_in[1];
    const float* qy   = (const float*)d_in[2];
    const float* bww  = (const float*)d_in[3];
    const float* cw   = (const float*)d_in[4];
    const float* cb   = (const float*)d_in[5];
    const float* wihf = (const float*)d_in[6];
    const float* whhf = (const float*)d_in[7];
    const float* bihf = (const float*)d_in[8];
    const float* bhhf = (const float*)d_in[9];
    const float* wihb = (const float*)d_in[10];
    const float* whhb = (const float*)d_in[11];
    const float* bihb = (const float*)d_in[12];
    const float* bhhb = (const float*)d_in[13];
    const float* w1   = (const float*)d_in[14];
    const float* b1   = (const float*)d_in[15];
    const float* w2   = (const float*)d_in[16];
    const float* b2   = (const float*)d_in[17];
    float* out = (float*)d_out;

    char* ws = (char*)d_ws;
    u16*   aout = (u16*)ws;                            // 256 KB used
    u16*   hout = (u16*)ws;                            // alias (aout dead after K2)
    u16*   xp3  = (u16*)(ws + (512 << 10));            // 1.5 MB
    u16*   Wf   = (u16*)(ws + (2u << 20));             // 384 KB
    float* Bf   = (float*)(ws + (2u << 20) + 384 * 1024);  // 3 KB

    k0_fuse<<<192, 256, 0, stream>>>(wihf, bihf, wihb, bihb, cw, cb, Wf, Bf);
    k1_attn<<<256, 1024, 0, stream>>>(x, ts, qy, bww, aout);
    k2_xp<<<768, 256, 0, stream>>>(aout, Wf, Bf, xp3);
    k3_gru<<<16, 512, 0, stream>>>(xp3, whhf, bhhf, whhb, bhhb, hout);
    k4_mlp<<<1024, 128, 0, stream>>>(hout, w1, b1, w2, b2, out);
}